// Round 21
// baseline (262.232 us; speedup 1.0000x reference)
//
#include <hip/hip_runtime.h>

#define KNN_K 8
constexpr int B = 32;
constexpr int N = 2048;
constexpr int M = B * N;  // 65536 points

typedef __attribute__((ext_vector_type(8))) short short8v;  // 8 bf16
typedef __attribute__((ext_vector_type(4))) float f32x4;

__device__ __forceinline__ float lrelu_max(float m, float y) {
  return fmaxf(m, fmaxf(y, 0.2f * y));
}
__device__ __forceinline__ unsigned short f2bf(float x) {  // RNE f32->bf16
  unsigned int u = __float_as_uint(x);
  unsigned int r = u + 0x7FFFu + ((u >> 16) & 1u);
  return (unsigned short)(r >> 16);
}
__device__ __forceinline__ float bf2f(unsigned short h) {
  return __uint_as_float(((unsigned int)h) << 16);
}

#define CAS_T(i, j)                                        \
  {                                                        \
    unsigned long long _x = t[i], _y = t[j];               \
    bool _p = _x < _y;                                     \
    t[i] = _p ? _y : _x;                                   \
    t[j] = _p ? _x : _y;                                   \
  }
#define CAS_TOP(i, j)                                      \
  {                                                        \
    unsigned long long _x = top[i], _y = top[j];           \
    bool _p = _x < _y;                                     \
    top[i] = _p ? _y : _x;                                 \
    top[j] = _p ? _x : _y;                                 \
  }

// ---- fused front end: knn (blk 0-1023) | layer-1 transform (1024-2047)
// ---- | wprep1 (2048-2079) | wprep2 (2080-2207).
__global__ __launch_bounds__(256) void front_kernel(
    const float* __restrict__ xyz, int* __restrict__ idx,
    const float* __restrict__ W0, const float* __restrict__ s0,
    const float* __restrict__ b0, float* __restrict__ G,
    float* __restrict__ C, const float* __restrict__ W1,
    const float* __restrict__ s1, unsigned short* __restrict__ wb1,
    const float* __restrict__ W2, const float* __restrict__ s2,
    unsigned short* __restrict__ wb2) {
  __shared__ __align__(16) char smem[32768];
  const int bid = (int)blockIdx.x;
  const int tid = (int)threadIdx.x;

  if (bid < 1024) {
    // ---------------- KNN (identical arithmetic to round-14) -------------
    float4* spt = (float4*)smem;  // [N]; reused as merge scratch
    int b = bid >> 5;
    int nblk = bid & 31;
    const float* F = xyz + (size_t)b * N * 3;
    for (int i = tid; i < N; i += 256) {
      float x = F[i], y = F[N + i], z = F[2 * N + i];
      spt[i] = make_float4(x, y, z, (x * x + y * y) + z * z);
    }
    __syncthreads();
    const int ln = tid >> 2;
    const int q = tid & 3;
    const int n = nblk * 64 + ln;
    float4 pn = spt[n];
    const float npnw = -pn.w;

    unsigned long long top[8];
    unsigned long long bufr[4];
#pragma unroll
    for (int k = 0; k < 8; ++k) top[k] = 0ull;
#pragma unroll
    for (int k = 0; k < 4; ++k) bufr[k] = 0ull;
    float thr = -1e30f;
    int cnt = 0;

    auto flush = [&]() {
      unsigned long long t[4];
#pragma unroll
      for (int i = 0; i < 4; ++i) t[i] = (i < cnt) ? bufr[i] : 0ull;
      CAS_T(0, 1) CAS_T(2, 3) CAS_T(0, 2) CAS_T(1, 3) CAS_T(1, 2)
      {
        unsigned long long x;
        x = top[4]; top[4] = x > t[3] ? x : t[3];
        x = top[5]; top[5] = x > t[2] ? x : t[2];
        x = top[6]; top[6] = x > t[1] ? x : t[1];
        x = top[7]; top[7] = x > t[0] ? x : t[0];
      }
      CAS_TOP(0, 4) CAS_TOP(1, 5) CAS_TOP(2, 6) CAS_TOP(3, 7)
      CAS_TOP(0, 2) CAS_TOP(1, 3) CAS_TOP(4, 6) CAS_TOP(5, 7)
      CAS_TOP(0, 1) CAS_TOP(2, 3) CAS_TOP(4, 5) CAS_TOP(6, 7)
      cnt = 0;
      if (top[7] != 0ull) {
        thr = __uint_as_float(~(unsigned int)(top[7] >> 32));
      }
    };

    unsigned int mnot = ~(unsigned int)q;
#pragma unroll 4
    for (int j = 0; j < N / 4; ++j) {
      int m = (j << 2) | q;
      float4 pm = spt[m];
      float dot = (pn.x * pm.x + pn.y * pm.y) + pn.z * pm.z;
      float pd = __builtin_fmaf(2.0f, dot, npnw) - pm.w;
      if (pd > thr) {
        unsigned long long key =
            ((unsigned long long)(~__float_as_uint(pd)) << 32) |
            (unsigned long long)mnot;
        bufr[3] = bufr[2]; bufr[2] = bufr[1]; bufr[1] = bufr[0];
        bufr[0] = key;
        ++cnt;
      }
      mnot -= 4u;
      if (__any(cnt >= 4)) flush();
    }
    flush();

    __syncthreads();
    unsigned long long* km = (unsigned long long*)smem;  // [256][8]
#pragma unroll
    for (int k = 0; k < 8; ++k) km[tid * 8 + k] = top[k];
    __syncthreads();
    if (q == 0) {
      int h[4] = {0, 0, 0, 0};
      int* op = idx + ((size_t)b * N + n) * KNN_K;
#pragma unroll
      for (int k = 0; k < KNN_K; ++k) {
        unsigned long long bk = 0ull;
        int bq = 0;
#pragma unroll
        for (int qq = 0; qq < 4; ++qq) {
          unsigned long long kk = km[(((ln << 2) | qq)) * 8 + h[qq]];
          if (kk > bk) { bk = kk; bq = qq; }
        }
        op[k] = (int)(0xFFFFFFFFu - (unsigned int)(bk & 0xFFFFFFFFull));
        h[bq]++;
      }
    }
  } else if (bid < 2048) {
    // -------------- layer-1 transform (CI=4 pad, CO=64), o0 = 0 ----------
    float* fs = (float*)smem;        // [4][68]
    float* was = fs + 4 * 68;        // [4][68]
    float* wds = was + 4 * 68;       // [4][68]
    const int base = (bid - 1024) * 64;
    const int tx = tid & 15, ty = tid >> 4;
    float accG[4][4] = {{0}};
    float accC[4][4] = {{0}};
    for (int i = tid; i < 64 * 4; i += 256) {
      int c = i & 3, p = i >> 2;
      fs[c * 68 + p] = (c < 3) ? xyz[(size_t)(base + p) * 3 + c] : 0.0f;
    }
    if (tid < 64) {
      int o = tid;
      float sc = s0[o];
      const float* wr = &W0[(size_t)o * 6];
#pragma unroll
      for (int c = 0; c < 4; ++c) {
        float wa = (c < 3) ? wr[c] : 0.0f;
        float wb = (c < 3) ? wr[3 + c] : 0.0f;
        was[c * 68 + o] = sc * wa;
        wds[c * 68 + o] = sc * (wb - wa);
      }
    }
    __syncthreads();
#pragma unroll
    for (int c = 0; c < 4; ++c) {
      float4 av = *(const float4*)&fs[c * 68 + ty * 4];
      float4 wg = *(const float4*)&was[c * 68 + tx * 4];
      float4 wd = *(const float4*)&wds[c * 68 + tx * 4];
      float a[4] = {av.x, av.y, av.z, av.w};
      float g[4] = {wg.x, wg.y, wg.z, wg.w};
      float d[4] = {wd.x, wd.y, wd.z, wd.w};
#pragma unroll
      for (int i = 0; i < 4; ++i)
#pragma unroll
        for (int j = 0; j < 4; ++j) {
          accG[i][j] = fmaf(a[i], g[j], accG[i][j]);
          accC[i][j] = fmaf(a[i], d[j], accC[i][j]);
        }
    }
    float4 sh = *(const float4*)&b0[tx * 4];
    float shv[4] = {sh.x, sh.y, sh.z, sh.w};
#pragma unroll
    for (int i = 0; i < 4; ++i) {
      size_t row = (size_t)(base + ty * 4 + i);
      float4 g4 = make_float4(accG[i][0], accG[i][1], accG[i][2], accG[i][3]);
      float4 c4 = make_float4(accC[i][0] + shv[0], accC[i][1] + shv[1],
                              accC[i][2] + shv[2], accC[i][3] + shv[3]);
      *(float4*)&G[row * 64 + tx * 4] = g4;
      *(float4*)&C[row * 64 + tx * 4] = c4;
    }
  } else if (bid < 2080) {
    // -------------- wprep layer 2: CI=64, CO=128 -> wb1 -------------------
    constexpr int CI = 64, CO = 128;
    int i = (bid - 2048) * 256 + tid;
    if (i < CI * CO) {
      int o = i / CI, k = i % CI;
      float sc = s1[o];
      float w0 = W1[(size_t)o * 2 * CI + k];
      float wa = sc * w0;
      float wd = sc * (W1[(size_t)o * 2 * CI + CI + k] - w0);
      unsigned short waH = f2bf(wa);
      unsigned short waL = f2bf(wa - bf2f(waH));
      unsigned short wdH = f2bf(wd);
      unsigned short wdL = f2bf(wd - bf2f(wdH));
      wb1[i] = waH;
      wb1[CI * CO + i] = waL;
      wb1[2 * CI * CO + i] = wdH;
      wb1[3 * CI * CO + i] = wdL;
    }
  } else {
    // -------------- wprep layer 3: CI=128, CO=256 -> wb2 ------------------
    constexpr int CI = 128, CO = 256;
    int i = (bid - 2080) * 256 + tid;
    if (i < CI * CO) {
      int o = i / CI, k = i % CI;
      float sc = s2[o];
      float w0 = W2[(size_t)o * 2 * CI + k];
      float wa = sc * w0;
      float wd = sc * (W2[(size_t)o * 2 * CI + CI + k] - w0);
      unsigned short waH = f2bf(wa);
      unsigned short waL = f2bf(wa - bf2f(waH));
      unsigned short wdH = f2bf(wd);
      unsigned short wdL = f2bf(wd - bf2f(wdH));
      wb2[i] = waH;
      wb2[CI * CO + i] = waL;
      wb2[2 * CI * CO + i] = wdH;
      wb2[3 * CI * CO + i] = wdL;
    }
  }
}

// --------- MFMA transform (2-pass): G = A·(Wh+Wl), C = A·(Wdh+Wdl) --------
// A is bf16-only features; W kept hi+lo (exact). Batch<->XCD co-location:
// blockIdx.x remapped so batch b's tiles land on XCD b%8 (matching the
// gather kernels' mapping) -> G/C stay in the producing XCD's L2 for the
// consumer. N/128 = 16 tiles per batch; 512 x-blocks = 4 groups x (8 x 16).
template <int K, int CO>
__global__ __launch_bounds__(256) void mfma_transform_kernel(
    const unsigned short* __restrict__ A, const unsigned short* __restrict__ wb,
    const float* __restrict__ bsh, float* __restrict__ G0,
    float* __restrict__ C0, float* __restrict__ G1, float* __restrict__ C1,
    size_t arrStride, size_t wbHalfOff, int bshHalfOff) {
  constexpr int KP = 40;  // padded LDS k-stride -> 80B rows, no 8-way conflict
  __shared__ unsigned short Ah[128][KP];
  __shared__ unsigned short Bw[4][64][KP];
  const int z = (int)blockIdx.z;
  const unsigned short* wbp = wb + (size_t)z * wbHalfOff;
  const float* bshp = bsh + z * bshHalfOff;
  float* G = z ? G1 : G0;
  float* C = z ? C1 : C0;
  // XCD-aware tile mapping: batch = grp*8 + (i%8), tile-in-batch = (i%128)/8
  const int i = (int)blockIdx.x;
  const int grp = i >> 7;
  const int jj = i & 127;
  const int batch = grp * 8 + (jj & 7);
  const int tib = jj >> 3;
  const int base = batch * N + tib * 128;
  const int o0 = blockIdx.y * 64;
  const int tid = (int)threadIdx.x;
  const int lane = tid & 63;
  const int wid = tid >> 6;
  const int wr = wid >> 1;  // wave row-half (64 pts)
  const int wc = wid & 1;   // wave col-half (32 outs)
  const int l15 = lane & 15;
  const int lk = (lane >> 4) * 8;  // fragment k-base

  f32x4 zero = {0.f, 0.f, 0.f, 0.f};
  f32x4 accG[4][2], accC[4][2];
#pragma unroll
  for (int a = 0; a < 4; ++a)
#pragma unroll
    for (int j = 0; j < 2; ++j) { accG[a][j] = zero; accC[a][j] = zero; }

  const int arow = tid >> 1;        // 0..127
  const int akh = (tid & 1) * 16;   // 0 / 16
  const int bo = tid & 63;          // weight out-row
  const int barr = tid >> 6;        // which of 4 arrays

  for (int kc0 = 0; kc0 < K; kc0 += 32) {
    {  // stage A: 128 x 32 bf16
      const unsigned short* pa = &A[(size_t)(base + arow) * K + kc0 + akh];
      short8v h0 = *(const short8v*)pa;
      short8v h1 = *(const short8v*)(pa + 8);
      *(short8v*)&Ah[arow][akh] = h0;
      *(short8v*)&Ah[arow][akh + 8] = h1;
      // stage B: 4 arrays x 64 outs x 32 k
      const unsigned short* pb =
          &wbp[(size_t)barr * arrStride + (size_t)(o0 + bo) * K + kc0];
#pragma unroll
      for (int j = 0; j < 4; ++j) {
        short8v v = *(const short8v*)(pb + j * 8);
        *(short8v*)&Bw[barr][bo][j * 8] = v;
      }
    }
    __syncthreads();
    short8v ah[4], bah[2], bal[2], bdh[2], bdl[2];
#pragma unroll
    for (int mf = 0; mf < 4; ++mf)
      ah[mf] = *(const short8v*)&Ah[wr * 64 + mf * 16 + l15][lk];
#pragma unroll
    for (int nf = 0; nf < 2; ++nf) {
      int oo = wc * 32 + nf * 16 + l15;
      bah[nf] = *(const short8v*)&Bw[0][oo][lk];
      bal[nf] = *(const short8v*)&Bw[1][oo][lk];
      bdh[nf] = *(const short8v*)&Bw[2][oo][lk];
      bdl[nf] = *(const short8v*)&Bw[3][oo][lk];
    }
#pragma unroll
    for (int mf = 0; mf < 4; ++mf)
#pragma unroll
      for (int nf = 0; nf < 2; ++nf) {
        accG[mf][nf] = __builtin_amdgcn_mfma_f32_16x16x32_bf16(
            ah[mf], bah[nf], accG[mf][nf], 0, 0, 0);
        accG[mf][nf] = __builtin_amdgcn_mfma_f32_16x16x32_bf16(
            ah[mf], bal[nf], accG[mf][nf], 0, 0, 0);
        accC[mf][nf] = __builtin_amdgcn_mfma_f32_16x16x32_bf16(
            ah[mf], bdh[nf], accC[mf][nf], 0, 0, 0);
        accC[mf][nf] = __builtin_amdgcn_mfma_f32_16x16x32_bf16(
            ah[mf], bdl[nf], accC[mf][nf], 0, 0, 0);
      }
    __syncthreads();
  }
  float sh[2];
  sh[0] = bshp[o0 + wc * 32 + l15];
  sh[1] = bshp[o0 + wc * 32 + 16 + l15];
#pragma unroll
  for (int mf = 0; mf < 4; ++mf)
#pragma unroll
    for (int nf = 0; nf < 2; ++nf) {
      int col = o0 + wc * 32 + nf * 16 + l15;
#pragma unroll
      for (int r = 0; r < 4; ++r) {
        int row = base + wr * 64 + mf * 16 + (lane >> 4) * 4 + r;
        G[(size_t)row * CO + col] = accG[mf][nf][r];
        C[(size_t)row * CO + col] = accC[mf][nf][r] + sh[nf];
      }
    }
}

// ------- gather + leaky + max over k; emits bf16 features (hi only) --------
// XCD-locality: batch = g*8 + (blockIdx%8) so a batch stays on one XCD L2.
template <int CO>
__global__ __launch_bounds__(256) void gatherbf_kernel(
    const float* __restrict__ G, const float* __restrict__ C,
    const int* __restrict__ idx, unsigned short* __restrict__ outHi) {
  constexpr int O4 = CO / 4;
  constexpr int PPB = 256 / O4;        // points per block
  constexpr int BPB = N / PPB;         // blocks per batch
  constexpr int GRP = 8 * BPB;         // blocks per batch-group
  const int i = (int)blockIdx.x;
  const int g = i / GRP;
  const int j = i % GRP;
  const int b = g * 8 + (j & 7);
  const int chunk = j >> 3;
  const int tid = (int)threadIdx.x;
  const int o4 = tid % O4;
  const int lp = tid / O4;
  const size_t bn = (size_t)b * N + chunk * PPB + lp;
  const int* ip = &idx[bn * KNN_K];
  const float* Gb = G + (size_t)b * N * CO;
  float4 cv = *(const float4*)&C[bn * CO + o4 * 4];
  float4 m = make_float4(-1e30f, -1e30f, -1e30f, -1e30f);
#pragma unroll
  for (int k = 0; k < KNN_K; ++k) {
    int nb = ip[k];
    float4 g4 = *(const float4*)&Gb[(size_t)nb * CO + o4 * 4];
    m.x = lrelu_max(m.x, g4.x + cv.x);
    m.y = lrelu_max(m.y, g4.y + cv.y);
    m.z = lrelu_max(m.z, g4.z + cv.z);
    m.w = lrelu_max(m.w, g4.w + cv.w);
  }
  ushort4 hi;
  hi.x = f2bf(m.x); hi.y = f2bf(m.y); hi.z = f2bf(m.z); hi.w = f2bf(m.w);
  *(ushort4*)&outHi[bn * CO + o4 * 4] = hi;
}

// ---------------- last layer: gather + max over k, partial max over n ------
// grid.y selects the output-channel half (fused path); same XCD mapping.
template <int CO>
__global__ __launch_bounds__(256) void gather_last_kernel(
    const float* __restrict__ G0, const float* __restrict__ C0,
    const float* __restrict__ G1, const float* __restrict__ C1,
    const int* __restrict__ idx, float* __restrict__ part) {
  constexpr int O4 = CO / 4;
  constexpr int PL = 256 / O4;
  constexpr int ITER = 128 / PL;
  const int h = (int)blockIdx.y;
  const float* G = h ? G1 : G0;
  const float* C = h ? C1 : C0;
  float* pt = part + (size_t)h * B * 16 * CO;
  const int i = (int)blockIdx.x;
  const int g = i / 128;
  const int j = i % 128;
  const int b = g * 8 + (j & 7);
  const int chunk = j >> 3;  // 0..15
  int tid = (int)threadIdx.x;
  int o4 = tid % O4;
  int pl = tid / O4;
  const float* Gb = G + (size_t)b * N * CO;
  float4 m = make_float4(-1e30f, -1e30f, -1e30f, -1e30f);
  for (int it = 0; it < ITER; ++it) {
    int n = chunk * 128 + it * PL + pl;
    size_t bn = (size_t)b * N + n;
    const int* ip = &idx[bn * KNN_K];
    float4 cv = *(const float4*)&C[bn * CO + o4 * 4];
#pragma unroll
    for (int k = 0; k < KNN_K; ++k) {
      int nb = ip[k];
      float4 g4 = *(const float4*)&Gb[(size_t)nb * CO + o4 * 4];
      m.x = lrelu_max(m.x, g4.x + cv.x);
      m.y = lrelu_max(m.y, g4.y + cv.y);
      m.z = lrelu_max(m.z, g4.z + cv.z);
      m.w = lrelu_max(m.w, g4.w + cv.w);
    }
  }
  __shared__ __align__(16) float4 red[256];
  red[tid] = m;
  __syncthreads();
  for (int s = 128; s >= O4; s >>= 1) {
    if (tid < s) {
      float4 a = red[tid], bb = red[tid + s];
      red[tid] = make_float4(fmaxf(a.x, bb.x), fmaxf(a.y, bb.y),
                             fmaxf(a.z, bb.z), fmaxf(a.w, bb.w));
    }
    __syncthreads();
  }
  if (tid < O4) {
    *(float4*)&pt[((size_t)(b * 16 + chunk)) * CO + tid * 4] = red[tid];
  }
}

// --------- fused final reduce over both 128-channel halves (grid.y=2) ------
template <int CO>
__global__ __launch_bounds__(256) void reduce2_kernel(const float* __restrict__ part,
                                                      float* __restrict__ out) {
  constexpr int O4 = CO / 4;
  int half = blockIdx.y;
  const float* p = part + (size_t)half * B * 16 * CO;
  int gid = blockIdx.x * 256 + (int)threadIdx.x;  // 0 .. B*O4-1
  int b = gid / O4;
  int o4 = gid % O4;
  float4 m = make_float4(-1e30f, -1e30f, -1e30f, -1e30f);
  for (int ch = 0; ch < 16; ++ch) {
    float4 v = *(const float4*)&p[((size_t)(b * 16 + ch)) * CO + o4 * 4];
    m.x = fmaxf(m.x, v.x); m.y = fmaxf(m.y, v.y);
    m.z = fmaxf(m.z, v.z); m.w = fmaxf(m.w, v.w);
  }
  *(float4*)&out[(size_t)b * 256 + half * 128 + o4 * 4] = m;
}

extern "C" void kernel_launch(void* const* d_in, const int* in_sizes, int n_in,
                              void* d_out, int out_size, void* d_ws, size_t ws_size,
                              hipStream_t stream) {
  const float* xyz = (const float*)d_in[0];
  const float* W0 = (const float*)d_in[1];
  const float* s0 = (const float*)d_in[2];
  const float* b0 = (const float*)d_in[3];
  const float* W1 = (const float*)d_in[4];
  const float* s1 = (const float*)d_in[5];
  const float* b1 = (const float*)d_in[6];
  const float* W2 = (const float*)d_in[7];
  const float* s2 = (const float*)d_in[8];
  const float* b2 = (const float*)d_in[9];
  float* out = (float*)d_out;

  const size_t MB = 1024 * 1024;
  const bool wide = ws_size >= 149 * MB;  // room for G2/C2 (fused layer-3)
  char* ws = (char*)d_ws;
  int* idx = (int*)ws;                                      // 2 MB
  unsigned short* Fb = (unsigned short*)(ws + 2 * MB);      // 16 MB bf16 feats
  float* G = (float*)(ws + 18 * MB);                        // 32 MB
  float* Cb = (float*)(ws + 50 * MB);                       // 32 MB
  float* G2 = wide ? (float*)(ws + 82 * MB) : G;            // 32 MB (wide)
  float* C2 = wide ? (float*)(ws + 114 * MB) : Cb;          // 32 MB (wide)
  size_t tail = wide ? 146 * MB : 82 * MB;
  unsigned short* wb1 = (unsigned short*)(ws + tail);            // 64 KB
  unsigned short* wb2 = (unsigned short*)(ws + tail + 64 * 1024);  // 256 KB
  float* part = (float*)(ws + tail + 512 * 1024);           // 512 KB (2 halves)

  // fused: knn (1024) | layer-1 transform (1024) | wprep1 (32) | wprep2 (128)
  front_kernel<<<2208, 256, 0, stream>>>(xyz, idx, W0, s0, b0, G, Cb, W1, s1,
                                         wb1, W2, s2, wb2);
  gatherbf_kernel<64><<<M * 16 / 256, 256, 0, stream>>>(G, Cb, idx, Fb);

  // Layer 2: K=64, CO=128 — MFMA 2-pass (W hi+lo, A bf16)
  mfma_transform_kernel<64, 128><<<dim3(M / 128, 2, 1), 256, 0, stream>>>(
      Fb, wb1, b1, G, Cb, G, Cb, (size_t)64 * 128, 0, 0);
  gatherbf_kernel<128><<<M * 32 / 256, 256, 0, stream>>>(G, Cb, idx, Fb);

  // Layer 3: K=128, CO=256 in two 128-channel halves — MFMA 2-pass
  if (wide) {
    mfma_transform_kernel<128, 128><<<dim3(M / 128, 2, 2), 256, 0, stream>>>(
        Fb, wb2, b2, G, Cb, G2, C2, (size_t)128 * 256, (size_t)128 * 128, 128);
    gather_last_kernel<128><<<dim3(B * 16, 2), 256, 0, stream>>>(
        G, Cb, G2, C2, idx, part);
  } else {
    for (int h = 0; h < 2; ++h) {
      mfma_transform_kernel<128, 128><<<dim3(M / 128, 2, 1), 256, 0, stream>>>(
          Fb, wb2 + (size_t)h * 128 * 128, b2 + h * 128, G, Cb, G, Cb,
          (size_t)128 * 256, 0, 0);
      gather_last_kernel<128><<<dim3(B * 16, 1), 256, 0, stream>>>(
          G, Cb, G, Cb, idx, part + (size_t)h * B * 16 * 128);
    }
  }
  reduce2_kernel<128><<<dim3(B * 128 / 4 / 256, 2), 256, 0, stream>>>(part, out);
}

// Round 22
// 256.811 us; speedup vs baseline: 1.0211x; 1.0211x over previous
//
#include <hip/hip_runtime.h>

#define KNN_K 8
constexpr int B = 32;
constexpr int N = 2048;
constexpr int M = B * N;  // 65536 points

typedef __attribute__((ext_vector_type(8))) short short8v;  // 8 bf16
typedef __attribute__((ext_vector_type(4))) float f32x4;

__device__ __forceinline__ float lrelu_max(float m, float y) {
  return fmaxf(m, fmaxf(y, 0.2f * y));
}
__device__ __forceinline__ unsigned short f2bf(float x) {  // RNE f32->bf16
  unsigned int u = __float_as_uint(x);
  unsigned int r = u + 0x7FFFu + ((u >> 16) & 1u);
  return (unsigned short)(r >> 16);
}
__device__ __forceinline__ float bf2f(unsigned short h) {
  return __uint_as_float(((unsigned int)h) << 16);
}

#define CAS_T(i, j)                                        \
  {                                                        \
    unsigned long long _x = t[i], _y = t[j];               \
    bool _p = _x < _y;                                     \
    t[i] = _p ? _y : _x;                                   \
    t[j] = _p ? _x : _y;                                   \
  }
#define CAS_TOP(i, j)                                      \
  {                                                        \
    unsigned long long _x = top[i], _y = top[j];           \
    bool _p = _x < _y;                                     \
    top[i] = _p ? _y : _x;                                 \
    top[j] = _p ? _x : _y;                                 \
  }

// ---- fused front end: knn (blk 0-1023) | layer-1 transform (1024-2047)
// ---- | wprep1 (2048-2079) | wprep2 (2080-2207).
__global__ __launch_bounds__(256) void front_kernel(
    const float* __restrict__ xyz, int* __restrict__ idx,
    const float* __restrict__ W0, const float* __restrict__ s0,
    const float* __restrict__ b0, float* __restrict__ G,
    float* __restrict__ C, const float* __restrict__ W1,
    const float* __restrict__ s1, unsigned short* __restrict__ wb1,
    const float* __restrict__ W2, const float* __restrict__ s2,
    unsigned short* __restrict__ wb2) {
  __shared__ __align__(16) char smem[32768];
  const int bid = (int)blockIdx.x;
  const int tid = (int)threadIdx.x;

  if (bid < 1024) {
    // ---------------- KNN with quad-shared threshold bound ---------------
    // Private lane bound (strict >) + quad bound qthr = min over the
    // query's 4 lanes of top[1] (>= keeps exact cross-lane tie order).
    // qthr is a lower bound on the union's final 8th => rejection exact.
    float4* spt = (float4*)smem;  // [N]; reused as merge scratch
    int b = bid >> 5;
    int nblk = bid & 31;
    const float* F = xyz + (size_t)b * N * 3;
    for (int i = tid; i < N; i += 256) {
      float x = F[i], y = F[N + i], z = F[2 * N + i];
      spt[i] = make_float4(x, y, z, (x * x + y * y) + z * z);
    }
    __syncthreads();
    const int ln = tid >> 2;
    const int q = tid & 3;
    const int n = nblk * 64 + ln;
    float4 pn = spt[n];
    const float npnw = -pn.w;

    unsigned long long top[8];
    unsigned long long bufr[4];
#pragma unroll
    for (int k = 0; k < 8; ++k) top[k] = 0ull;
#pragma unroll
    for (int k = 0; k < 4; ++k) bufr[k] = 0ull;
    float thr = -1e30f;   // own top[7] (strict >)
    float qthr = -1e30f;  // quad-shared bound (>=)
    int cnt = 0;

    auto flush = [&]() {
      unsigned long long t[4];
#pragma unroll
      for (int i = 0; i < 4; ++i) t[i] = (i < cnt) ? bufr[i] : 0ull;
      CAS_T(0, 1) CAS_T(2, 3) CAS_T(0, 2) CAS_T(1, 3) CAS_T(1, 2)
      {
        unsigned long long x;
        x = top[4]; top[4] = x > t[3] ? x : t[3];
        x = top[5]; top[5] = x > t[2] ? x : t[2];
        x = top[6]; top[6] = x > t[1] ? x : t[1];
        x = top[7]; top[7] = x > t[0] ? x : t[0];
      }
      CAS_TOP(0, 4) CAS_TOP(1, 5) CAS_TOP(2, 6) CAS_TOP(3, 7)
      CAS_TOP(0, 2) CAS_TOP(1, 3) CAS_TOP(4, 6) CAS_TOP(5, 7)
      CAS_TOP(0, 1) CAS_TOP(2, 3) CAS_TOP(4, 5) CAS_TOP(6, 7)
      cnt = 0;
      if (top[7] != 0ull) {
        thr = __uint_as_float(~(unsigned int)(top[7] >> 32));
      }
      // quad bound: min over 4 lanes of top[1] = min of 8 known union
      // elements => lower bound on the union's (current and final) 8th.
      float nb = (top[1] != 0ull)
                     ? __uint_as_float(~(unsigned int)(top[1] >> 32))
                     : -1e30f;
      nb = fminf(nb, __shfl_xor(nb, 1));
      nb = fminf(nb, __shfl_xor(nb, 2));
      qthr = nb;
    };

    unsigned int mnot = ~(unsigned int)q;
#pragma unroll 4
    for (int j = 0; j < N / 4; ++j) {
      int m = (j << 2) | q;
      float4 pm = spt[m];
      float dot = (pn.x * pm.x + pn.y * pm.y) + pn.z * pm.z;
      float pd = __builtin_fmaf(2.0f, dot, npnw) - pm.w;
      if (pd > thr && pd >= qthr) {
        unsigned long long key =
            ((unsigned long long)(~__float_as_uint(pd)) << 32) |
            (unsigned long long)mnot;
        bufr[3] = bufr[2]; bufr[2] = bufr[1]; bufr[1] = bufr[0];
        bufr[0] = key;
        ++cnt;
      }
      mnot -= 4u;
      if (__any(cnt >= 4)) flush();
    }
    flush();

    __syncthreads();
    unsigned long long* km = (unsigned long long*)smem;  // [256][8]
#pragma unroll
    for (int k = 0; k < 8; ++k) km[tid * 8 + k] = top[k];
    __syncthreads();
    if (q == 0) {
      int h[4] = {0, 0, 0, 0};
      int* op = idx + ((size_t)b * N + n) * KNN_K;
#pragma unroll
      for (int k = 0; k < KNN_K; ++k) {
        unsigned long long bk = 0ull;
        int bq = 0;
#pragma unroll
        for (int qq = 0; qq < 4; ++qq) {
          unsigned long long kk = km[(((ln << 2) | qq)) * 8 + h[qq]];
          if (kk > bk) { bk = kk; bq = qq; }
        }
        op[k] = (int)(0xFFFFFFFFu - (unsigned int)(bk & 0xFFFFFFFFull));
        h[bq]++;
      }
    }
  } else if (bid < 2048) {
    // -------------- layer-1 transform (CI=4 pad, CO=64), o0 = 0 ----------
    float* fs = (float*)smem;        // [4][68]
    float* was = fs + 4 * 68;        // [4][68]
    float* wds = was + 4 * 68;       // [4][68]
    const int base = (bid - 1024) * 64;
    const int tx = tid & 15, ty = tid >> 4;
    float accG[4][4] = {{0}};
    float accC[4][4] = {{0}};
    for (int i = tid; i < 64 * 4; i += 256) {
      int c = i & 3, p = i >> 2;
      fs[c * 68 + p] = (c < 3) ? xyz[(size_t)(base + p) * 3 + c] : 0.0f;
    }
    if (tid < 64) {
      int o = tid;
      float sc = s0[o];
      const float* wr = &W0[(size_t)o * 6];
#pragma unroll
      for (int c = 0; c < 4; ++c) {
        float wa = (c < 3) ? wr[c] : 0.0f;
        float wb = (c < 3) ? wr[3 + c] : 0.0f;
        was[c * 68 + o] = sc * wa;
        wds[c * 68 + o] = sc * (wb - wa);
      }
    }
    __syncthreads();
#pragma unroll
    for (int c = 0; c < 4; ++c) {
      float4 av = *(const float4*)&fs[c * 68 + ty * 4];
      float4 wg = *(const float4*)&was[c * 68 + tx * 4];
      float4 wd = *(const float4*)&wds[c * 68 + tx * 4];
      float a[4] = {av.x, av.y, av.z, av.w};
      float g[4] = {wg.x, wg.y, wg.z, wg.w};
      float d[4] = {wd.x, wd.y, wd.z, wd.w};
#pragma unroll
      for (int i = 0; i < 4; ++i)
#pragma unroll
        for (int j = 0; j < 4; ++j) {
          accG[i][j] = fmaf(a[i], g[j], accG[i][j]);
          accC[i][j] = fmaf(a[i], d[j], accC[i][j]);
        }
    }
    float4 sh = *(const float4*)&b0[tx * 4];
    float shv[4] = {sh.x, sh.y, sh.z, sh.w};
#pragma unroll
    for (int i = 0; i < 4; ++i) {
      size_t row = (size_t)(base + ty * 4 + i);
      float4 g4 = make_float4(accG[i][0], accG[i][1], accG[i][2], accG[i][3]);
      float4 c4 = make_float4(accC[i][0] + shv[0], accC[i][1] + shv[1],
                              accC[i][2] + shv[2], accC[i][3] + shv[3]);
      *(float4*)&G[row * 64 + tx * 4] = g4;
      *(float4*)&C[row * 64 + tx * 4] = c4;
    }
  } else if (bid < 2080) {
    // -------------- wprep layer 2: CI=64, CO=128 -> wb1 -------------------
    constexpr int CI = 64, CO = 128;
    int i = (bid - 2048) * 256 + tid;
    if (i < CI * CO) {
      int o = i / CI, k = i % CI;
      float sc = s1[o];
      float w0 = W1[(size_t)o * 2 * CI + k];
      float wa = sc * w0;
      float wd = sc * (W1[(size_t)o * 2 * CI + CI + k] - w0);
      unsigned short waH = f2bf(wa);
      unsigned short waL = f2bf(wa - bf2f(waH));
      unsigned short wdH = f2bf(wd);
      unsigned short wdL = f2bf(wd - bf2f(wdH));
      wb1[i] = waH;
      wb1[CI * CO + i] = waL;
      wb1[2 * CI * CO + i] = wdH;
      wb1[3 * CI * CO + i] = wdL;
    }
  } else {
    // -------------- wprep layer 3: CI=128, CO=256 -> wb2 ------------------
    constexpr int CI = 128, CO = 256;
    int i = (bid - 2080) * 256 + tid;
    if (i < CI * CO) {
      int o = i / CI, k = i % CI;
      float sc = s2[o];
      float w0 = W2[(size_t)o * 2 * CI + k];
      float wa = sc * w0;
      float wd = sc * (W2[(size_t)o * 2 * CI + CI + k] - w0);
      unsigned short waH = f2bf(wa);
      unsigned short waL = f2bf(wa - bf2f(waH));
      unsigned short wdH = f2bf(wd);
      unsigned short wdL = f2bf(wd - bf2f(wdH));
      wb2[i] = waH;
      wb2[CI * CO + i] = waL;
      wb2[2 * CI * CO + i] = wdH;
      wb2[3 * CI * CO + i] = wdL;
    }
  }
}

// --------- MFMA transform (2-pass): G = A·(Wh+Wl), C = A·(Wdh+Wdl) --------
// A is bf16-only features; W kept hi+lo (exact). Batch<->XCD co-location.
template <int K, int CO>
__global__ __launch_bounds__(256) void mfma_transform_kernel(
    const unsigned short* __restrict__ A, const unsigned short* __restrict__ wb,
    const float* __restrict__ bsh, float* __restrict__ G0,
    float* __restrict__ C0, float* __restrict__ G1, float* __restrict__ C1,
    size_t arrStride, size_t wbHalfOff, int bshHalfOff) {
  constexpr int KP = 40;  // padded LDS k-stride -> 80B rows, no 8-way conflict
  __shared__ unsigned short Ah[128][KP];
  __shared__ unsigned short Bw[4][64][KP];
  const int z = (int)blockIdx.z;
  const unsigned short* wbp = wb + (size_t)z * wbHalfOff;
  const float* bshp = bsh + z * bshHalfOff;
  float* G = z ? G1 : G0;
  float* C = z ? C1 : C0;
  const int i = (int)blockIdx.x;
  const int grp = i >> 7;
  const int jj = i & 127;
  const int batch = grp * 8 + (jj & 7);
  const int tib = jj >> 3;
  const int base = batch * N + tib * 128;
  const int o0 = blockIdx.y * 64;
  const int tid = (int)threadIdx.x;
  const int lane = tid & 63;
  const int wid = tid >> 6;
  const int wr = wid >> 1;  // wave row-half (64 pts)
  const int wc = wid & 1;   // wave col-half (32 outs)
  const int l15 = lane & 15;
  const int lk = (lane >> 4) * 8;  // fragment k-base

  f32x4 zero = {0.f, 0.f, 0.f, 0.f};
  f32x4 accG[4][2], accC[4][2];
#pragma unroll
  for (int a = 0; a < 4; ++a)
#pragma unroll
    for (int j = 0; j < 2; ++j) { accG[a][j] = zero; accC[a][j] = zero; }

  const int arow = tid >> 1;        // 0..127
  const int akh = (tid & 1) * 16;   // 0 / 16
  const int bo = tid & 63;          // weight out-row
  const int barr = tid >> 6;        // which of 4 arrays

  for (int kc0 = 0; kc0 < K; kc0 += 32) {
    {  // stage A: 128 x 32 bf16
      const unsigned short* pa = &A[(size_t)(base + arow) * K + kc0 + akh];
      short8v h0 = *(const short8v*)pa;
      short8v h1 = *(const short8v*)(pa + 8);
      *(short8v*)&Ah[arow][akh] = h0;
      *(short8v*)&Ah[arow][akh + 8] = h1;
      // stage B: 4 arrays x 64 outs x 32 k
      const unsigned short* pb =
          &wbp[(size_t)barr * arrStride + (size_t)(o0 + bo) * K + kc0];
#pragma unroll
      for (int j = 0; j < 4; ++j) {
        short8v v = *(const short8v*)(pb + j * 8);
        *(short8v*)&Bw[barr][bo][j * 8] = v;
      }
    }
    __syncthreads();
    short8v ah[4], bah[2], bal[2], bdh[2], bdl[2];
#pragma unroll
    for (int mf = 0; mf < 4; ++mf)
      ah[mf] = *(const short8v*)&Ah[wr * 64 + mf * 16 + l15][lk];
#pragma unroll
    for (int nf = 0; nf < 2; ++nf) {
      int oo = wc * 32 + nf * 16 + l15;
      bah[nf] = *(const short8v*)&Bw[0][oo][lk];
      bal[nf] = *(const short8v*)&Bw[1][oo][lk];
      bdh[nf] = *(const short8v*)&Bw[2][oo][lk];
      bdl[nf] = *(const short8v*)&Bw[3][oo][lk];
    }
#pragma unroll
    for (int mf = 0; mf < 4; ++mf)
#pragma unroll
      for (int nf = 0; nf < 2; ++nf) {
        accG[mf][nf] = __builtin_amdgcn_mfma_f32_16x16x32_bf16(
            ah[mf], bah[nf], accG[mf][nf], 0, 0, 0);
        accG[mf][nf] = __builtin_amdgcn_mfma_f32_16x16x32_bf16(
            ah[mf], bal[nf], accG[mf][nf], 0, 0, 0);
        accC[mf][nf] = __builtin_amdgcn_mfma_f32_16x16x32_bf16(
            ah[mf], bdh[nf], accC[mf][nf], 0, 0, 0);
        accC[mf][nf] = __builtin_amdgcn_mfma_f32_16x16x32_bf16(
            ah[mf], bdl[nf], accC[mf][nf], 0, 0, 0);
      }
    __syncthreads();
  }
  float sh[2];
  sh[0] = bshp[o0 + wc * 32 + l15];
  sh[1] = bshp[o0 + wc * 32 + 16 + l15];
#pragma unroll
  for (int mf = 0; mf < 4; ++mf)
#pragma unroll
    for (int nf = 0; nf < 2; ++nf) {
      int col = o0 + wc * 32 + nf * 16 + l15;
#pragma unroll
      for (int r = 0; r < 4; ++r) {
        int row = base + wr * 64 + mf * 16 + (lane >> 4) * 4 + r;
        G[(size_t)row * CO + col] = accG[mf][nf][r];
        C[(size_t)row * CO + col] = accC[mf][nf][r] + sh[nf];
      }
    }
}

// ------- gather + leaky + max over k; emits bf16 features (hi only) --------
template <int CO>
__global__ __launch_bounds__(256) void gatherbf_kernel(
    const float* __restrict__ G, const float* __restrict__ C,
    const int* __restrict__ idx, unsigned short* __restrict__ outHi) {
  constexpr int O4 = CO / 4;
  constexpr int PPB = 256 / O4;        // points per block
  constexpr int BPB = N / PPB;         // blocks per batch
  constexpr int GRP = 8 * BPB;         // blocks per batch-group
  const int i = (int)blockIdx.x;
  const int g = i / GRP;
  const int j = i % GRP;
  const int b = g * 8 + (j & 7);
  const int chunk = j >> 3;
  const int tid = (int)threadIdx.x;
  const int o4 = tid % O4;
  const int lp = tid / O4;
  const size_t bn = (size_t)b * N + chunk * PPB + lp;
  const int* ip = &idx[bn * KNN_K];
  const float* Gb = G + (size_t)b * N * CO;
  float4 cv = *(const float4*)&C[bn * CO + o4 * 4];
  float4 m = make_float4(-1e30f, -1e30f, -1e30f, -1e30f);
#pragma unroll
  for (int k = 0; k < KNN_K; ++k) {
    int nb = ip[k];
    float4 g4 = *(const float4*)&Gb[(size_t)nb * CO + o4 * 4];
    m.x = lrelu_max(m.x, g4.x + cv.x);
    m.y = lrelu_max(m.y, g4.y + cv.y);
    m.z = lrelu_max(m.z, g4.z + cv.z);
    m.w = lrelu_max(m.w, g4.w + cv.w);
  }
  ushort4 hi;
  hi.x = f2bf(m.x); hi.y = f2bf(m.y); hi.z = f2bf(m.z); hi.w = f2bf(m.w);
  *(ushort4*)&outHi[bn * CO + o4 * 4] = hi;
}

// ---------------- last layer: gather + max over k, partial max over n ------
template <int CO>
__global__ __launch_bounds__(256) void gather_last_kernel(
    const float* __restrict__ G0, const float* __restrict__ C0,
    const float* __restrict__ G1, const float* __restrict__ C1,
    const int* __restrict__ idx, float* __restrict__ part) {
  constexpr int O4 = CO / 4;
  constexpr int PL = 256 / O4;
  constexpr int ITER = 128 / PL;
  const int h = (int)blockIdx.y;
  const float* G = h ? G1 : G0;
  const float* C = h ? C1 : C0;
  float* pt = part + (size_t)h * B * 16 * CO;
  const int i = (int)blockIdx.x;
  const int g = i / 128;
  const int j = i % 128;
  const int b = g * 8 + (j & 7);
  const int chunk = j >> 3;  // 0..15
  int tid = (int)threadIdx.x;
  int o4 = tid % O4;
  int pl = tid / O4;
  const float* Gb = G + (size_t)b * N * CO;
  float4 m = make_float4(-1e30f, -1e30f, -1e30f, -1e30f);
  for (int it = 0; it < ITER; ++it) {
    int n = chunk * 128 + it * PL + pl;
    size_t bn = (size_t)b * N + n;
    const int* ip = &idx[bn * KNN_K];
    float4 cv = *(const float4*)&C[bn * CO + o4 * 4];
#pragma unroll
    for (int k = 0; k < KNN_K; ++k) {
      int nb = ip[k];
      float4 g4 = *(const float4*)&Gb[(size_t)nb * CO + o4 * 4];
      m.x = lrelu_max(m.x, g4.x + cv.x);
      m.y = lrelu_max(m.y, g4.y + cv.y);
      m.z = lrelu_max(m.z, g4.z + cv.z);
      m.w = lrelu_max(m.w, g4.w + cv.w);
    }
  }
  __shared__ __align__(16) float4 red[256];
  red[tid] = m;
  __syncthreads();
  for (int s = 128; s >= O4; s >>= 1) {
    if (tid < s) {
      float4 a = red[tid], bb = red[tid + s];
      red[tid] = make_float4(fmaxf(a.x, bb.x), fmaxf(a.y, bb.y),
                             fmaxf(a.z, bb.z), fmaxf(a.w, bb.w));
    }
    __syncthreads();
  }
  if (tid < O4) {
    *(float4*)&pt[((size_t)(b * 16 + chunk)) * CO + tid * 4] = red[tid];
  }
}

// --------- fused final reduce over both 128-channel halves (grid.y=2) ------
template <int CO>
__global__ __launch_bounds__(256) void reduce2_kernel(const float* __restrict__ part,
                                                      float* __restrict__ out) {
  constexpr int O4 = CO / 4;
  int half = blockIdx.y;
  const float* p = part + (size_t)half * B * 16 * CO;
  int gid = blockIdx.x * 256 + (int)threadIdx.x;  // 0 .. B*O4-1
  int b = gid / O4;
  int o4 = gid % O4;
  float4 m = make_float4(-1e30f, -1e30f, -1e30f, -1e30f);
  for (int ch = 0; ch < 16; ++ch) {
    float4 v = *(const float4*)&p[((size_t)(b * 16 + ch)) * CO + o4 * 4];
    m.x = fmaxf(m.x, v.x); m.y = fmaxf(m.y, v.y);
    m.z = fmaxf(m.z, v.z); m.w = fmaxf(m.w, v.w);
  }
  *(float4*)&out[(size_t)b * 256 + half * 128 + o4 * 4] = m;
}

extern "C" void kernel_launch(void* const* d_in, const int* in_sizes, int n_in,
                              void* d_out, int out_size, void* d_ws, size_t ws_size,
                              hipStream_t stream) {
  const float* xyz = (const float*)d_in[0];
  const float* W0 = (const float*)d_in[1];
  const float* s0 = (const float*)d_in[2];
  const float* b0 = (const float*)d_in[3];
  const float* W1 = (const float*)d_in[4];
  const float* s1 = (const float*)d_in[5];
  const float* b1 = (const float*)d_in[6];
  const float* W2 = (const float*)d_in[7];
  const float* s2 = (const float*)d_in[8];
  const float* b2 = (const float*)d_in[9];
  float* out = (float*)d_out;

  const size_t MB = 1024 * 1024;
  const bool wide = ws_size >= 149 * MB;  // room for G2/C2 (fused layer-3)
  char* ws = (char*)d_ws;
  int* idx = (int*)ws;                                      // 2 MB
  unsigned short* Fb = (unsigned short*)(ws + 2 * MB);      // 16 MB bf16 feats
  float* G = (float*)(ws + 18 * MB);                        // 32 MB
  float* Cb = (float*)(ws + 50 * MB);                       // 32 MB
  float* G2 = wide ? (float*)(ws + 82 * MB) : G;            // 32 MB (wide)
  float* C2 = wide ? (float*)(ws + 114 * MB) : Cb;          // 32 MB (wide)
  size_t tail = wide ? 146 * MB : 82 * MB;
  unsigned short* wb1 = (unsigned short*)(ws + tail);            // 64 KB
  unsigned short* wb2 = (unsigned short*)(ws + tail + 64 * 1024);  // 256 KB
  float* part = (float*)(ws + tail + 512 * 1024);           // 512 KB (2 halves)

  // fused: knn (1024) | layer-1 transform (1024) | wprep1 (32) | wprep2 (128)
  front_kernel<<<2208, 256, 0, stream>>>(xyz, idx, W0, s0, b0, G, Cb, W1, s1,
                                         wb1, W2, s2, wb2);
  gatherbf_kernel<64><<<M * 16 / 256, 256, 0, stream>>>(G, Cb, idx, Fb);

  // Layer 2: K=64, CO=128 — MFMA 2-pass (W hi+lo, A bf16)
  mfma_transform_kernel<64, 128><<<dim3(M / 128, 2, 1), 256, 0, stream>>>(
      Fb, wb1, b1, G, Cb, G, Cb, (size_t)64 * 128, 0, 0);
  gatherbf_kernel<128><<<M * 32 / 256, 256, 0, stream>>>(G, Cb, idx, Fb);

  // Layer 3: K=128, CO=256 in two 128-channel halves — MFMA 2-pass
  if (wide) {
    mfma_transform_kernel<128, 128><<<dim3(M / 128, 2, 2), 256, 0, stream>>>(
        Fb, wb2, b2, G, Cb, G2, C2, (size_t)128 * 256, (size_t)128 * 128, 128);
    gather_last_kernel<128><<<dim3(B * 16, 2), 256, 0, stream>>>(
        G, Cb, G2, C2, idx, part);
  } else {
    for (int h = 0; h < 2; ++h) {
      mfma_transform_kernel<128, 128><<<dim3(M / 128, 2, 1), 256, 0, stream>>>(
          Fb, wb2 + (size_t)h * 128 * 128, b2 + h * 128, G, Cb, G, Cb,
          (size_t)128 * 256, 0, 0);
      gather_last_kernel<128><<<dim3(B * 16, 1), 256, 0, stream>>>(
          G, Cb, G, Cb, idx, part + (size_t)h * B * 16 * 128);
    }
  }
  reduce2_kernel<128><<<dim3(B * 128 / 4 / 256, 2), 256, 0, stream>>>(part, out);
}

// Round 23
// 220.616 us; speedup vs baseline: 1.1886x; 1.1641x over previous
//
#include <hip/hip_runtime.h>

#define KNN_K 8
constexpr int B = 32;
constexpr int N = 2048;
constexpr int M = B * N;  // 65536 points

typedef __attribute__((ext_vector_type(8))) short short8v;  // 8 bf16
typedef __attribute__((ext_vector_type(4))) float f32x4;

__device__ __forceinline__ float lrelu_max(float m, float y) {
  return fmaxf(m, fmaxf(y, 0.2f * y));
}
__device__ __forceinline__ unsigned short f2bf(float x) {  // RNE f32->bf16
  unsigned int u = __float_as_uint(x);
  unsigned int r = u + 0x7FFFu + ((u >> 16) & 1u);
  return (unsigned short)(r >> 16);
}
__device__ __forceinline__ float bf2f(unsigned short h) {
  return __uint_as_float(((unsigned int)h) << 16);
}

#define CAS_T(i, j)                                        \
  {                                                        \
    unsigned long long _x = t[i], _y = t[j];               \
    bool _p = _x < _y;                                     \
    t[i] = _p ? _y : _x;                                   \
    t[j] = _p ? _x : _y;                                   \
  }
#define CAS_TOP(i, j)                                      \
  {                                                        \
    unsigned long long _x = top[i], _y = top[j];           \
    bool _p = _x < _y;                                     \
    top[i] = _p ? _y : _x;                                 \
    top[j] = _p ? _x : _y;                                 \
  }

// ---- fused front end: knn (blk 0-1023) | layer-1 transform (1024-2047)
// ---- | wprep1 (2048-2079) | wprep2 (2080-2207). G stored as bf16.
__global__ __launch_bounds__(256) void front_kernel(
    const float* __restrict__ xyz, int* __restrict__ idx,
    const float* __restrict__ W0, const float* __restrict__ s0,
    const float* __restrict__ b0, unsigned short* __restrict__ G,
    float* __restrict__ C, const float* __restrict__ W1,
    const float* __restrict__ s1, unsigned short* __restrict__ wb1,
    const float* __restrict__ W2, const float* __restrict__ s2,
    unsigned short* __restrict__ wb2) {
  __shared__ __align__(16) char smem[32768];
  const int bid = (int)blockIdx.x;
  const int tid = (int)threadIdx.x;

  if (bid < 1024) {
    // ---------------- KNN with quad-shared threshold bound ---------------
    float4* spt = (float4*)smem;  // [N]; reused as merge scratch
    int b = bid >> 5;
    int nblk = bid & 31;
    const float* F = xyz + (size_t)b * N * 3;
    for (int i = tid; i < N; i += 256) {
      float x = F[i], y = F[N + i], z = F[2 * N + i];
      spt[i] = make_float4(x, y, z, (x * x + y * y) + z * z);
    }
    __syncthreads();
    const int ln = tid >> 2;
    const int q = tid & 3;
    const int n = nblk * 64 + ln;
    float4 pn = spt[n];
    const float npnw = -pn.w;

    unsigned long long top[8];
    unsigned long long bufr[4];
#pragma unroll
    for (int k = 0; k < 8; ++k) top[k] = 0ull;
#pragma unroll
    for (int k = 0; k < 4; ++k) bufr[k] = 0ull;
    float thr = -1e30f;   // own top[7] (strict >)
    float qthr = -1e30f;  // quad-shared bound (>=)
    int cnt = 0;

    auto flush = [&]() {
      unsigned long long t[4];
#pragma unroll
      for (int i = 0; i < 4; ++i) t[i] = (i < cnt) ? bufr[i] : 0ull;
      CAS_T(0, 1) CAS_T(2, 3) CAS_T(0, 2) CAS_T(1, 3) CAS_T(1, 2)
      {
        unsigned long long x;
        x = top[4]; top[4] = x > t[3] ? x : t[3];
        x = top[5]; top[5] = x > t[2] ? x : t[2];
        x = top[6]; top[6] = x > t[1] ? x : t[1];
        x = top[7]; top[7] = x > t[0] ? x : t[0];
      }
      CAS_TOP(0, 4) CAS_TOP(1, 5) CAS_TOP(2, 6) CAS_TOP(3, 7)
      CAS_TOP(0, 2) CAS_TOP(1, 3) CAS_TOP(4, 6) CAS_TOP(5, 7)
      CAS_TOP(0, 1) CAS_TOP(2, 3) CAS_TOP(4, 5) CAS_TOP(6, 7)
      cnt = 0;
      if (top[7] != 0ull) {
        thr = __uint_as_float(~(unsigned int)(top[7] >> 32));
      }
      float nb = (top[1] != 0ull)
                     ? __uint_as_float(~(unsigned int)(top[1] >> 32))
                     : -1e30f;
      nb = fminf(nb, __shfl_xor(nb, 1));
      nb = fminf(nb, __shfl_xor(nb, 2));
      qthr = nb;
    };

    unsigned int mnot = ~(unsigned int)q;
#pragma unroll 4
    for (int j = 0; j < N / 4; ++j) {
      int m = (j << 2) | q;
      float4 pm = spt[m];
      float dot = (pn.x * pm.x + pn.y * pm.y) + pn.z * pm.z;
      float pd = __builtin_fmaf(2.0f, dot, npnw) - pm.w;
      if (pd > thr && pd >= qthr) {
        unsigned long long key =
            ((unsigned long long)(~__float_as_uint(pd)) << 32) |
            (unsigned long long)mnot;
        bufr[3] = bufr[2]; bufr[2] = bufr[1]; bufr[1] = bufr[0];
        bufr[0] = key;
        ++cnt;
      }
      mnot -= 4u;
      if (__any(cnt >= 4)) flush();
    }
    flush();

    __syncthreads();
    unsigned long long* km = (unsigned long long*)smem;  // [256][8]
#pragma unroll
    for (int k = 0; k < 8; ++k) km[tid * 8 + k] = top[k];
    __syncthreads();
    if (q == 0) {
      int h[4] = {0, 0, 0, 0};
      int* op = idx + ((size_t)b * N + n) * KNN_K;
#pragma unroll
      for (int k = 0; k < KNN_K; ++k) {
        unsigned long long bk = 0ull;
        int bq = 0;
#pragma unroll
        for (int qq = 0; qq < 4; ++qq) {
          unsigned long long kk = km[(((ln << 2) | qq)) * 8 + h[qq]];
          if (kk > bk) { bk = kk; bq = qq; }
        }
        op[k] = (int)(0xFFFFFFFFu - (unsigned int)(bk & 0xFFFFFFFFull));
        h[bq]++;
      }
    }
  } else if (bid < 2048) {
    // -------------- layer-1 transform (CI=4 pad, CO=64), o0 = 0 ----------
    float* fs = (float*)smem;        // [4][68]
    float* was = fs + 4 * 68;        // [4][68]
    float* wds = was + 4 * 68;       // [4][68]
    const int base = (bid - 1024) * 64;
    const int tx = tid & 15, ty = tid >> 4;
    float accG[4][4] = {{0}};
    float accC[4][4] = {{0}};
    for (int i = tid; i < 64 * 4; i += 256) {
      int c = i & 3, p = i >> 2;
      fs[c * 68 + p] = (c < 3) ? xyz[(size_t)(base + p) * 3 + c] : 0.0f;
    }
    if (tid < 64) {
      int o = tid;
      float sc = s0[o];
      const float* wr = &W0[(size_t)o * 6];
#pragma unroll
      for (int c = 0; c < 4; ++c) {
        float wa = (c < 3) ? wr[c] : 0.0f;
        float wb = (c < 3) ? wr[3 + c] : 0.0f;
        was[c * 68 + o] = sc * wa;
        wds[c * 68 + o] = sc * (wb - wa);
      }
    }
    __syncthreads();
#pragma unroll
    for (int c = 0; c < 4; ++c) {
      float4 av = *(const float4*)&fs[c * 68 + ty * 4];
      float4 wg = *(const float4*)&was[c * 68 + tx * 4];
      float4 wd = *(const float4*)&wds[c * 68 + tx * 4];
      float a[4] = {av.x, av.y, av.z, av.w};
      float g[4] = {wg.x, wg.y, wg.z, wg.w};
      float d[4] = {wd.x, wd.y, wd.z, wd.w};
#pragma unroll
      for (int i = 0; i < 4; ++i)
#pragma unroll
        for (int j = 0; j < 4; ++j) {
          accG[i][j] = fmaf(a[i], g[j], accG[i][j]);
          accC[i][j] = fmaf(a[i], d[j], accC[i][j]);
        }
    }
    float4 sh = *(const float4*)&b0[tx * 4];
    float shv[4] = {sh.x, sh.y, sh.z, sh.w};
#pragma unroll
    for (int i = 0; i < 4; ++i) {
      size_t row = (size_t)(base + ty * 4 + i);
      ushort4 g4;
      g4.x = f2bf(accG[i][0]); g4.y = f2bf(accG[i][1]);
      g4.z = f2bf(accG[i][2]); g4.w = f2bf(accG[i][3]);
      float4 c4 = make_float4(accC[i][0] + shv[0], accC[i][1] + shv[1],
                              accC[i][2] + shv[2], accC[i][3] + shv[3]);
      *(ushort4*)&G[row * 64 + tx * 4] = g4;
      *(float4*)&C[row * 64 + tx * 4] = c4;
    }
  } else if (bid < 2080) {
    // -------------- wprep layer 2: CI=64, CO=128 -> wb1 -------------------
    constexpr int CI = 64, CO = 128;
    int i = (bid - 2048) * 256 + tid;
    if (i < CI * CO) {
      int o = i / CI, k = i % CI;
      float sc = s1[o];
      float w0 = W1[(size_t)o * 2 * CI + k];
      float wa = sc * w0;
      float wd = sc * (W1[(size_t)o * 2 * CI + CI + k] - w0);
      unsigned short waH = f2bf(wa);
      unsigned short waL = f2bf(wa - bf2f(waH));
      unsigned short wdH = f2bf(wd);
      unsigned short wdL = f2bf(wd - bf2f(wdH));
      wb1[i] = waH;
      wb1[CI * CO + i] = waL;
      wb1[2 * CI * CO + i] = wdH;
      wb1[3 * CI * CO + i] = wdL;
    }
  } else {
    // -------------- wprep layer 3: CI=128, CO=256 -> wb2 ------------------
    constexpr int CI = 128, CO = 256;
    int i = (bid - 2080) * 256 + tid;
    if (i < CI * CO) {
      int o = i / CI, k = i % CI;
      float sc = s2[o];
      float w0 = W2[(size_t)o * 2 * CI + k];
      float wa = sc * w0;
      float wd = sc * (W2[(size_t)o * 2 * CI + CI + k] - w0);
      unsigned short waH = f2bf(wa);
      unsigned short waL = f2bf(wa - bf2f(waH));
      unsigned short wdH = f2bf(wd);
      unsigned short wdL = f2bf(wd - bf2f(wdH));
      wb2[i] = waH;
      wb2[CI * CO + i] = waL;
      wb2[2 * CI * CO + i] = wdH;
      wb2[3 * CI * CO + i] = wdL;
    }
  }
}

// --------- MFMA transform (2-pass): G(bf16) = A·(Wh+Wl), C = A·(Wdh+Wdl) --
// A is bf16-only features; W kept hi+lo (exact). Batch<->XCD co-location.
template <int K, int CO>
__global__ __launch_bounds__(256) void mfma_transform_kernel(
    const unsigned short* __restrict__ A, const unsigned short* __restrict__ wb,
    const float* __restrict__ bsh, unsigned short* __restrict__ G0,
    float* __restrict__ C0, unsigned short* __restrict__ G1,
    float* __restrict__ C1, size_t arrStride, size_t wbHalfOff,
    int bshHalfOff) {
  constexpr int KP = 40;  // padded LDS k-stride -> 80B rows, no 8-way conflict
  __shared__ unsigned short Ah[128][KP];
  __shared__ unsigned short Bw[4][64][KP];
  const int z = (int)blockIdx.z;
  const unsigned short* wbp = wb + (size_t)z * wbHalfOff;
  const float* bshp = bsh + z * bshHalfOff;
  unsigned short* G = z ? G1 : G0;
  float* C = z ? C1 : C0;
  const int i = (int)blockIdx.x;
  const int grp = i >> 7;
  const int jj = i & 127;
  const int batch = grp * 8 + (jj & 7);
  const int tib = jj >> 3;
  const int base = batch * N + tib * 128;
  const int o0 = blockIdx.y * 64;
  const int tid = (int)threadIdx.x;
  const int lane = tid & 63;
  const int wid = tid >> 6;
  const int wr = wid >> 1;  // wave row-half (64 pts)
  const int wc = wid & 1;   // wave col-half (32 outs)
  const int l15 = lane & 15;
  const int lk = (lane >> 4) * 8;  // fragment k-base

  f32x4 zero = {0.f, 0.f, 0.f, 0.f};
  f32x4 accG[4][2], accC[4][2];
#pragma unroll
  for (int a = 0; a < 4; ++a)
#pragma unroll
    for (int j = 0; j < 2; ++j) { accG[a][j] = zero; accC[a][j] = zero; }

  const int arow = tid >> 1;        // 0..127
  const int akh = (tid & 1) * 16;   // 0 / 16
  const int bo = tid & 63;          // weight out-row
  const int barr = tid >> 6;        // which of 4 arrays

  for (int kc0 = 0; kc0 < K; kc0 += 32) {
    {  // stage A: 128 x 32 bf16
      const unsigned short* pa = &A[(size_t)(base + arow) * K + kc0 + akh];
      short8v h0 = *(const short8v*)pa;
      short8v h1 = *(const short8v*)(pa + 8);
      *(short8v*)&Ah[arow][akh] = h0;
      *(short8v*)&Ah[arow][akh + 8] = h1;
      // stage B: 4 arrays x 64 outs x 32 k
      const unsigned short* pb =
          &wbp[(size_t)barr * arrStride + (size_t)(o0 + bo) * K + kc0];
#pragma unroll
      for (int j = 0; j < 4; ++j) {
        short8v v = *(const short8v*)(pb + j * 8);
        *(short8v*)&Bw[barr][bo][j * 8] = v;
      }
    }
    __syncthreads();
    short8v ah[4], bah[2], bal[2], bdh[2], bdl[2];
#pragma unroll
    for (int mf = 0; mf < 4; ++mf)
      ah[mf] = *(const short8v*)&Ah[wr * 64 + mf * 16 + l15][lk];
#pragma unroll
    for (int nf = 0; nf < 2; ++nf) {
      int oo = wc * 32 + nf * 16 + l15;
      bah[nf] = *(const short8v*)&Bw[0][oo][lk];
      bal[nf] = *(const short8v*)&Bw[1][oo][lk];
      bdh[nf] = *(const short8v*)&Bw[2][oo][lk];
      bdl[nf] = *(const short8v*)&Bw[3][oo][lk];
    }
#pragma unroll
    for (int mf = 0; mf < 4; ++mf)
#pragma unroll
      for (int nf = 0; nf < 2; ++nf) {
        accG[mf][nf] = __builtin_amdgcn_mfma_f32_16x16x32_bf16(
            ah[mf], bah[nf], accG[mf][nf], 0, 0, 0);
        accG[mf][nf] = __builtin_amdgcn_mfma_f32_16x16x32_bf16(
            ah[mf], bal[nf], accG[mf][nf], 0, 0, 0);
        accC[mf][nf] = __builtin_amdgcn_mfma_f32_16x16x32_bf16(
            ah[mf], bdh[nf], accC[mf][nf], 0, 0, 0);
        accC[mf][nf] = __builtin_amdgcn_mfma_f32_16x16x32_bf16(
            ah[mf], bdl[nf], accC[mf][nf], 0, 0, 0);
      }
    __syncthreads();
  }
  float sh[2];
  sh[0] = bshp[o0 + wc * 32 + l15];
  sh[1] = bshp[o0 + wc * 32 + 16 + l15];
#pragma unroll
  for (int mf = 0; mf < 4; ++mf)
#pragma unroll
    for (int nf = 0; nf < 2; ++nf) {
      int col = o0 + wc * 32 + nf * 16 + l15;
#pragma unroll
      for (int r = 0; r < 4; ++r) {
        int row = base + wr * 64 + mf * 16 + (lane >> 4) * 4 + r;
        G[(size_t)row * CO + col] = f2bf(accG[mf][nf][r]);
        C[(size_t)row * CO + col] = accC[mf][nf][r] + sh[nf];
      }
    }
}

// ------- gather + leaky + max over k; G read as bf16, C as f32 -------------
// XCD-locality: batch = g*8 + (blockIdx%8) so a batch stays on one XCD L2.
template <int CO>
__global__ __launch_bounds__(256) void gatherbf_kernel(
    const unsigned short* __restrict__ G, const float* __restrict__ C,
    const int* __restrict__ idx, unsigned short* __restrict__ outHi) {
  constexpr int O4 = CO / 4;
  constexpr int PPB = 256 / O4;        // points per block
  constexpr int BPB = N / PPB;         // blocks per batch
  constexpr int GRP = 8 * BPB;         // blocks per batch-group
  const int i = (int)blockIdx.x;
  const int g = i / GRP;
  const int j = i % GRP;
  const int b = g * 8 + (j & 7);
  const int chunk = j >> 3;
  const int tid = (int)threadIdx.x;
  const int o4 = tid % O4;
  const int lp = tid / O4;
  const size_t bn = (size_t)b * N + chunk * PPB + lp;
  const int* ip = &idx[bn * KNN_K];
  const unsigned short* Gb = G + (size_t)b * N * CO;
  float4 cv = *(const float4*)&C[bn * CO + o4 * 4];
  float4 m = make_float4(-1e30f, -1e30f, -1e30f, -1e30f);
#pragma unroll
  for (int k = 0; k < KNN_K; ++k) {
    int nb = ip[k];
    ushort4 gu = *(const ushort4*)&Gb[(size_t)nb * CO + o4 * 4];
    m.x = lrelu_max(m.x, bf2f(gu.x) + cv.x);
    m.y = lrelu_max(m.y, bf2f(gu.y) + cv.y);
    m.z = lrelu_max(m.z, bf2f(gu.z) + cv.z);
    m.w = lrelu_max(m.w, bf2f(gu.w) + cv.w);
  }
  ushort4 hi;
  hi.x = f2bf(m.x); hi.y = f2bf(m.y); hi.z = f2bf(m.z); hi.w = f2bf(m.w);
  *(ushort4*)&outHi[bn * CO + o4 * 4] = hi;
}

// ---------------- last layer: gather + max over k, partial max over n ------
template <int CO>
__global__ __launch_bounds__(256) void gather_last_kernel(
    const unsigned short* __restrict__ G0, const float* __restrict__ C0,
    const unsigned short* __restrict__ G1, const float* __restrict__ C1,
    const int* __restrict__ idx, float* __restrict__ part) {
  constexpr int O4 = CO / 4;
  constexpr int PL = 256 / O4;
  constexpr int ITER = 128 / PL;
  const int h = (int)blockIdx.y;
  const unsigned short* G = h ? G1 : G0;
  const float* C = h ? C1 : C0;
  float* pt = part + (size_t)h * B * 16 * CO;
  const int i = (int)blockIdx.x;
  const int g = i / 128;
  const int j = i % 128;
  const int b = g * 8 + (j & 7);
  const int chunk = j >> 3;  // 0..15
  int tid = (int)threadIdx.x;
  int o4 = tid % O4;
  int pl = tid / O4;
  const unsigned short* Gb = G + (size_t)b * N * CO;
  float4 m = make_float4(-1e30f, -1e30f, -1e30f, -1e30f);
  for (int it = 0; it < ITER; ++it) {
    int n = chunk * 128 + it * PL + pl;
    size_t bn = (size_t)b * N + n;
    const int* ip = &idx[bn * KNN_K];
    float4 cv = *(const float4*)&C[bn * CO + o4 * 4];
#pragma unroll
    for (int k = 0; k < KNN_K; ++k) {
      int nb = ip[k];
      ushort4 gu = *(const ushort4*)&Gb[(size_t)nb * CO + o4 * 4];
      m.x = lrelu_max(m.x, bf2f(gu.x) + cv.x);
      m.y = lrelu_max(m.y, bf2f(gu.y) + cv.y);
      m.z = lrelu_max(m.z, bf2f(gu.z) + cv.z);
      m.w = lrelu_max(m.w, bf2f(gu.w) + cv.w);
    }
  }
  __shared__ __align__(16) float4 red[256];
  red[tid] = m;
  __syncthreads();
  for (int s = 128; s >= O4; s >>= 1) {
    if (tid < s) {
      float4 a = red[tid], bb = red[tid + s];
      red[tid] = make_float4(fmaxf(a.x, bb.x), fmaxf(a.y, bb.y),
                             fmaxf(a.z, bb.z), fmaxf(a.w, bb.w));
    }
    __syncthreads();
  }
  if (tid < O4) {
    *(float4*)&pt[((size_t)(b * 16 + chunk)) * CO + tid * 4] = red[tid];
  }
}

// --------- fused final reduce over both 128-channel halves (grid.y=2) ------
template <int CO>
__global__ __launch_bounds__(256) void reduce2_kernel(const float* __restrict__ part,
                                                      float* __restrict__ out) {
  constexpr int O4 = CO / 4;
  int half = blockIdx.y;
  const float* p = part + (size_t)half * B * 16 * CO;
  int gid = blockIdx.x * 256 + (int)threadIdx.x;  // 0 .. B*O4-1
  int b = gid / O4;
  int o4 = gid % O4;
  float4 m = make_float4(-1e30f, -1e30f, -1e30f, -1e30f);
  for (int ch = 0; ch < 16; ++ch) {
    float4 v = *(const float4*)&p[((size_t)(b * 16 + ch)) * CO + o4 * 4];
    m.x = fmaxf(m.x, v.x); m.y = fmaxf(m.y, v.y);
    m.z = fmaxf(m.z, v.z); m.w = fmaxf(m.w, v.w);
  }
  *(float4*)&out[(size_t)b * 256 + half * 128 + o4 * 4] = m;
}

extern "C" void kernel_launch(void* const* d_in, const int* in_sizes, int n_in,
                              void* d_out, int out_size, void* d_ws, size_t ws_size,
                              hipStream_t stream) {
  const float* xyz = (const float*)d_in[0];
  const float* W0 = (const float*)d_in[1];
  const float* s0 = (const float*)d_in[2];
  const float* b0 = (const float*)d_in[3];
  const float* W1 = (const float*)d_in[4];
  const float* s1 = (const float*)d_in[5];
  const float* b1 = (const float*)d_in[6];
  const float* W2 = (const float*)d_in[7];
  const float* s2 = (const float*)d_in[8];
  const float* b2 = (const float*)d_in[9];
  float* out = (float*)d_out;

  const size_t MB = 1024 * 1024;
  const bool wide = ws_size >= 118 * MB;  // room for G2/C2 (fused layer-3)
  char* ws = (char*)d_ws;
  int* idx = (int*)ws;                                       // 2 MB
  unsigned short* Fb = (unsigned short*)(ws + 2 * MB);       // 16 MB bf16 feats
  unsigned short* Gb = (unsigned short*)(ws + 18 * MB);      // 16 MB bf16 G
  float* Cb = (float*)(ws + 34 * MB);                        // 32 MB
  unsigned short* G2 = wide ? (unsigned short*)(ws + 66 * MB) : Gb;  // 16 MB
  float* C2 = wide ? (float*)(ws + 82 * MB) : Cb;            // 32 MB (wide)
  size_t tail = wide ? 114 * MB : 66 * MB;
  unsigned short* wb1 = (unsigned short*)(ws + tail);              // 64 KB
  unsigned short* wb2 = (unsigned short*)(ws + tail + 64 * 1024);  // 256 KB
  float* part = (float*)(ws + tail + 512 * 1024);            // 512 KB (2 halves)

  // fused: knn (1024) | layer-1 transform (1024) | wprep1 (32) | wprep2 (128)
  front_kernel<<<2208, 256, 0, stream>>>(xyz, idx, W0, s0, b0, Gb, Cb, W1, s1,
                                         wb1, W2, s2, wb2);
  gatherbf_kernel<64><<<M * 16 / 256, 256, 0, stream>>>(Gb, Cb, idx, Fb);

  // Layer 2: K=64, CO=128 — MFMA 2-pass (W hi+lo, A bf16)
  mfma_transform_kernel<64, 128><<<dim3(M / 128, 2, 1), 256, 0, stream>>>(
      Fb, wb1, b1, Gb, Cb, Gb, Cb, (size_t)64 * 128, 0, 0);
  gatherbf_kernel<128><<<M * 32 / 256, 256, 0, stream>>>(Gb, Cb, idx, Fb);

  // Layer 3: K=128, CO=256 in two 128-channel halves — MFMA 2-pass
  if (wide) {
    mfma_transform_kernel<128, 128><<<dim3(M / 128, 2, 2), 256, 0, stream>>>(
        Fb, wb2, b2, Gb, Cb, G2, C2, (size_t)128 * 256, (size_t)128 * 128, 128);
    gather_last_kernel<128><<<dim3(B * 16, 2), 256, 0, stream>>>(
        Gb, Cb, G2, C2, idx, part);
  } else {
    for (int h = 0; h < 2; ++h) {
      mfma_transform_kernel<128, 128><<<dim3(M / 128, 2, 1), 256, 0, stream>>>(
          Fb, wb2 + (size_t)h * 128 * 128, b2 + h * 128, Gb, Cb, Gb, Cb,
          (size_t)128 * 256, 0, 0);
      gather_last_kernel<128><<<dim3(B * 16, 1), 256, 0, stream>>>(
          Gb, Cb, Gb, Cb, idx, part + (size_t)h * B * 16 * 128);
    }
  }
  reduce2_kernel<128><<<dim3(B * 128 / 4 / 256, 2), 256, 0, stream>>>(part, out);
}

// Round 24
// 212.173 us; speedup vs baseline: 1.2359x; 1.0398x over previous
//
#include <hip/hip_runtime.h>

#define KNN_K 8
constexpr int B = 32;
constexpr int N = 2048;
constexpr int M = B * N;  // 65536 points

typedef __attribute__((ext_vector_type(8))) short short8v;  // 8 bf16
typedef __attribute__((ext_vector_type(4))) float f32x4;

__device__ __forceinline__ float lrelu_max(float m, float y) {
  return fmaxf(m, fmaxf(y, 0.2f * y));
}
__device__ __forceinline__ unsigned short f2bf(float x) {  // RNE f32->bf16
  unsigned int u = __float_as_uint(x);
  unsigned int r = u + 0x7FFFu + ((u >> 16) & 1u);
  return (unsigned short)(r >> 16);
}
__device__ __forceinline__ float bf2f(unsigned short h) {
  return __uint_as_float(((unsigned int)h) << 16);
}

#define CAS_T(i, j)                                        \
  {                                                        \
    unsigned long long _x = t[i], _y = t[j];               \
    bool _p = _x < _y;                                     \
    t[i] = _p ? _y : _x;                                   \
    t[j] = _p ? _x : _y;                                   \
  }
#define CAS_TOP(i, j)                                      \
  {                                                        \
    unsigned long long _x = top[i], _y = top[j];           \
    bool _p = _x < _y;                                     \
    top[i] = _p ? _y : _x;                                 \
    top[j] = _p ? _x : _y;                                 \
  }

// ---- fused front end: knn (blk 0-1023) | layer-1 transform (1024-2047)
// ---- | wprep1 (2048-2079) | wprep2 (2080-2207). G and C stored as bf16.
__global__ __launch_bounds__(256) void front_kernel(
    const float* __restrict__ xyz, int* __restrict__ idx,
    const float* __restrict__ W0, const float* __restrict__ s0,
    const float* __restrict__ b0, unsigned short* __restrict__ G,
    unsigned short* __restrict__ C, const float* __restrict__ W1,
    const float* __restrict__ s1, unsigned short* __restrict__ wb1,
    const float* __restrict__ W2, const float* __restrict__ s2,
    unsigned short* __restrict__ wb2) {
  __shared__ __align__(16) char smem[32768];
  const int bid = (int)blockIdx.x;
  const int tid = (int)threadIdx.x;

  if (bid < 1024) {
    // ---------------- KNN with quad-shared threshold bound ---------------
    float4* spt = (float4*)smem;  // [N]; reused as merge scratch
    int b = bid >> 5;
    int nblk = bid & 31;
    const float* F = xyz + (size_t)b * N * 3;
    for (int i = tid; i < N; i += 256) {
      float x = F[i], y = F[N + i], z = F[2 * N + i];
      spt[i] = make_float4(x, y, z, (x * x + y * y) + z * z);
    }
    __syncthreads();
    const int ln = tid >> 2;
    const int q = tid & 3;
    const int n = nblk * 64 + ln;
    float4 pn = spt[n];
    const float npnw = -pn.w;

    unsigned long long top[8];
    unsigned long long bufr[4];
#pragma unroll
    for (int k = 0; k < 8; ++k) top[k] = 0ull;
#pragma unroll
    for (int k = 0; k < 4; ++k) bufr[k] = 0ull;
    float thr = -1e30f;   // own top[7] (strict >)
    float qthr = -1e30f;  // quad-shared bound (>=)
    int cnt = 0;

    auto flush = [&]() {
      unsigned long long t[4];
#pragma unroll
      for (int i = 0; i < 4; ++i) t[i] = (i < cnt) ? bufr[i] : 0ull;
      CAS_T(0, 1) CAS_T(2, 3) CAS_T(0, 2) CAS_T(1, 3) CAS_T(1, 2)
      {
        unsigned long long x;
        x = top[4]; top[4] = x > t[3] ? x : t[3];
        x = top[5]; top[5] = x > t[2] ? x : t[2];
        x = top[6]; top[6] = x > t[1] ? x : t[1];
        x = top[7]; top[7] = x > t[0] ? x : t[0];
      }
      CAS_TOP(0, 4) CAS_TOP(1, 5) CAS_TOP(2, 6) CAS_TOP(3, 7)
      CAS_TOP(0, 2) CAS_TOP(1, 3) CAS_TOP(4, 6) CAS_TOP(5, 7)
      CAS_TOP(0, 1) CAS_TOP(2, 3) CAS_TOP(4, 5) CAS_TOP(6, 7)
      cnt = 0;
      if (top[7] != 0ull) {
        thr = __uint_as_float(~(unsigned int)(top[7] >> 32));
      }
      float nb = (top[1] != 0ull)
                     ? __uint_as_float(~(unsigned int)(top[1] >> 32))
                     : -1e30f;
      nb = fminf(nb, __shfl_xor(nb, 1));
      nb = fminf(nb, __shfl_xor(nb, 2));
      qthr = nb;
    };

    unsigned int mnot = ~(unsigned int)q;
#pragma unroll 4
    for (int j = 0; j < N / 4; ++j) {
      int m = (j << 2) | q;
      float4 pm = spt[m];
      float dot = (pn.x * pm.x + pn.y * pm.y) + pn.z * pm.z;
      float pd = __builtin_fmaf(2.0f, dot, npnw) - pm.w;
      if (pd > thr && pd >= qthr) {
        unsigned long long key =
            ((unsigned long long)(~__float_as_uint(pd)) << 32) |
            (unsigned long long)mnot;
        bufr[3] = bufr[2]; bufr[2] = bufr[1]; bufr[1] = bufr[0];
        bufr[0] = key;
        ++cnt;
      }
      mnot -= 4u;
      if (__any(cnt >= 4)) flush();
    }
    flush();

    __syncthreads();
    unsigned long long* km = (unsigned long long*)smem;  // [256][8]
#pragma unroll
    for (int k = 0; k < 8; ++k) km[tid * 8 + k] = top[k];
    __syncthreads();
    if (q == 0) {
      int h[4] = {0, 0, 0, 0};
      int* op = idx + ((size_t)b * N + n) * KNN_K;
#pragma unroll
      for (int k = 0; k < KNN_K; ++k) {
        unsigned long long bk = 0ull;
        int bq = 0;
#pragma unroll
        for (int qq = 0; qq < 4; ++qq) {
          unsigned long long kk = km[(((ln << 2) | qq)) * 8 + h[qq]];
          if (kk > bk) { bk = kk; bq = qq; }
        }
        op[k] = (int)(0xFFFFFFFFu - (unsigned int)(bk & 0xFFFFFFFFull));
        h[bq]++;
      }
    }
  } else if (bid < 2048) {
    // -------------- layer-1 transform (CI=4 pad, CO=64), o0 = 0 ----------
    float* fs = (float*)smem;        // [4][68]
    float* was = fs + 4 * 68;        // [4][68]
    float* wds = was + 4 * 68;       // [4][68]
    const int base = (bid - 1024) * 64;
    const int tx = tid & 15, ty = tid >> 4;
    float accG[4][4] = {{0}};
    float accC[4][4] = {{0}};
    for (int i = tid; i < 64 * 4; i += 256) {
      int c = i & 3, p = i >> 2;
      fs[c * 68 + p] = (c < 3) ? xyz[(size_t)(base + p) * 3 + c] : 0.0f;
    }
    if (tid < 64) {
      int o = tid;
      float sc = s0[o];
      const float* wr = &W0[(size_t)o * 6];
#pragma unroll
      for (int c = 0; c < 4; ++c) {
        float wa = (c < 3) ? wr[c] : 0.0f;
        float wb = (c < 3) ? wr[3 + c] : 0.0f;
        was[c * 68 + o] = sc * wa;
        wds[c * 68 + o] = sc * (wb - wa);
      }
    }
    __syncthreads();
#pragma unroll
    for (int c = 0; c < 4; ++c) {
      float4 av = *(const float4*)&fs[c * 68 + ty * 4];
      float4 wg = *(const float4*)&was[c * 68 + tx * 4];
      float4 wd = *(const float4*)&wds[c * 68 + tx * 4];
      float a[4] = {av.x, av.y, av.z, av.w};
      float g[4] = {wg.x, wg.y, wg.z, wg.w};
      float d[4] = {wd.x, wd.y, wd.z, wd.w};
#pragma unroll
      for (int i = 0; i < 4; ++i)
#pragma unroll
        for (int j = 0; j < 4; ++j) {
          accG[i][j] = fmaf(a[i], g[j], accG[i][j]);
          accC[i][j] = fmaf(a[i], d[j], accC[i][j]);
        }
    }
    float4 sh = *(const float4*)&b0[tx * 4];
    float shv[4] = {sh.x, sh.y, sh.z, sh.w};
#pragma unroll
    for (int i = 0; i < 4; ++i) {
      size_t row = (size_t)(base + ty * 4 + i);
      ushort4 g4, c4;
      g4.x = f2bf(accG[i][0]); g4.y = f2bf(accG[i][1]);
      g4.z = f2bf(accG[i][2]); g4.w = f2bf(accG[i][3]);
      c4.x = f2bf(accC[i][0] + shv[0]); c4.y = f2bf(accC[i][1] + shv[1]);
      c4.z = f2bf(accC[i][2] + shv[2]); c4.w = f2bf(accC[i][3] + shv[3]);
      *(ushort4*)&G[row * 64 + tx * 4] = g4;
      *(ushort4*)&C[row * 64 + tx * 4] = c4;
    }
  } else if (bid < 2080) {
    // -------------- wprep layer 2: CI=64, CO=128 -> wb1 -------------------
    constexpr int CI = 64, CO = 128;
    int i = (bid - 2048) * 256 + tid;
    if (i < CI * CO) {
      int o = i / CI, k = i % CI;
      float sc = s1[o];
      float w0 = W1[(size_t)o * 2 * CI + k];
      float wa = sc * w0;
      float wd = sc * (W1[(size_t)o * 2 * CI + CI + k] - w0);
      unsigned short waH = f2bf(wa);
      unsigned short waL = f2bf(wa - bf2f(waH));
      unsigned short wdH = f2bf(wd);
      unsigned short wdL = f2bf(wd - bf2f(wdH));
      wb1[i] = waH;
      wb1[CI * CO + i] = waL;
      wb1[2 * CI * CO + i] = wdH;
      wb1[3 * CI * CO + i] = wdL;
    }
  } else {
    // -------------- wprep layer 3: CI=128, CO=256 -> wb2 ------------------
    constexpr int CI = 128, CO = 256;
    int i = (bid - 2080) * 256 + tid;
    if (i < CI * CO) {
      int o = i / CI, k = i % CI;
      float sc = s2[o];
      float w0 = W2[(size_t)o * 2 * CI + k];
      float wa = sc * w0;
      float wd = sc * (W2[(size_t)o * 2 * CI + CI + k] - w0);
      unsigned short waH = f2bf(wa);
      unsigned short waL = f2bf(wa - bf2f(waH));
      unsigned short wdH = f2bf(wd);
      unsigned short wdL = f2bf(wd - bf2f(wdH));
      wb2[i] = waH;
      wb2[CI * CO + i] = waL;
      wb2[2 * CI * CO + i] = wdH;
      wb2[3 * CI * CO + i] = wdL;
    }
  }
}

// --------- MFMA transform (2-pass): G,C (bf16) = A·W(hi+lo) ---------------
// A is bf16-only features; W kept hi+lo (exact). Batch<->XCD co-location.
template <int K, int CO>
__global__ __launch_bounds__(256) void mfma_transform_kernel(
    const unsigned short* __restrict__ A, const unsigned short* __restrict__ wb,
    const float* __restrict__ bsh, unsigned short* __restrict__ G0,
    unsigned short* __restrict__ C0, unsigned short* __restrict__ G1,
    unsigned short* __restrict__ C1, size_t arrStride, size_t wbHalfOff,
    int bshHalfOff) {
  constexpr int KP = 40;  // padded LDS k-stride -> 80B rows, no 8-way conflict
  __shared__ unsigned short Ah[128][KP];
  __shared__ unsigned short Bw[4][64][KP];
  const int z = (int)blockIdx.z;
  const unsigned short* wbp = wb + (size_t)z * wbHalfOff;
  const float* bshp = bsh + z * bshHalfOff;
  unsigned short* G = z ? G1 : G0;
  unsigned short* C = z ? C1 : C0;
  const int i = (int)blockIdx.x;
  const int grp = i >> 7;
  const int jj = i & 127;
  const int batch = grp * 8 + (jj & 7);
  const int tib = jj >> 3;
  const int base = batch * N + tib * 128;
  const int o0 = blockIdx.y * 64;
  const int tid = (int)threadIdx.x;
  const int lane = tid & 63;
  const int wid = tid >> 6;
  const int wr = wid >> 1;  // wave row-half (64 pts)
  const int wc = wid & 1;   // wave col-half (32 outs)
  const int l15 = lane & 15;
  const int lk = (lane >> 4) * 8;  // fragment k-base

  f32x4 zero = {0.f, 0.f, 0.f, 0.f};
  f32x4 accG[4][2], accC[4][2];
#pragma unroll
  for (int a = 0; a < 4; ++a)
#pragma unroll
    for (int j = 0; j < 2; ++j) { accG[a][j] = zero; accC[a][j] = zero; }

  const int arow = tid >> 1;        // 0..127
  const int akh = (tid & 1) * 16;   // 0 / 16
  const int bo = tid & 63;          // weight out-row
  const int barr = tid >> 6;        // which of 4 arrays

  for (int kc0 = 0; kc0 < K; kc0 += 32) {
    {  // stage A: 128 x 32 bf16
      const unsigned short* pa = &A[(size_t)(base + arow) * K + kc0 + akh];
      short8v h0 = *(const short8v*)pa;
      short8v h1 = *(const short8v*)(pa + 8);
      *(short8v*)&Ah[arow][akh] = h0;
      *(short8v*)&Ah[arow][akh + 8] = h1;
      // stage B: 4 arrays x 64 outs x 32 k
      const unsigned short* pb =
          &wbp[(size_t)barr * arrStride + (size_t)(o0 + bo) * K + kc0];
#pragma unroll
      for (int j = 0; j < 4; ++j) {
        short8v v = *(const short8v*)(pb + j * 8);
        *(short8v*)&Bw[barr][bo][j * 8] = v;
      }
    }
    __syncthreads();
    short8v ah[4], bah[2], bal[2], bdh[2], bdl[2];
#pragma unroll
    for (int mf = 0; mf < 4; ++mf)
      ah[mf] = *(const short8v*)&Ah[wr * 64 + mf * 16 + l15][lk];
#pragma unroll
    for (int nf = 0; nf < 2; ++nf) {
      int oo = wc * 32 + nf * 16 + l15;
      bah[nf] = *(const short8v*)&Bw[0][oo][lk];
      bal[nf] = *(const short8v*)&Bw[1][oo][lk];
      bdh[nf] = *(const short8v*)&Bw[2][oo][lk];
      bdl[nf] = *(const short8v*)&Bw[3][oo][lk];
    }
#pragma unroll
    for (int mf = 0; mf < 4; ++mf)
#pragma unroll
      for (int nf = 0; nf < 2; ++nf) {
        accG[mf][nf] = __builtin_amdgcn_mfma_f32_16x16x32_bf16(
            ah[mf], bah[nf], accG[mf][nf], 0, 0, 0);
        accG[mf][nf] = __builtin_amdgcn_mfma_f32_16x16x32_bf16(
            ah[mf], bal[nf], accG[mf][nf], 0, 0, 0);
        accC[mf][nf] = __builtin_amdgcn_mfma_f32_16x16x32_bf16(
            ah[mf], bdh[nf], accC[mf][nf], 0, 0, 0);
        accC[mf][nf] = __builtin_amdgcn_mfma_f32_16x16x32_bf16(
            ah[mf], bdl[nf], accC[mf][nf], 0, 0, 0);
      }
    __syncthreads();
  }
  float sh[2];
  sh[0] = bshp[o0 + wc * 32 + l15];
  sh[1] = bshp[o0 + wc * 32 + 16 + l15];
#pragma unroll
  for (int mf = 0; mf < 4; ++mf)
#pragma unroll
    for (int nf = 0; nf < 2; ++nf) {
      int col = o0 + wc * 32 + nf * 16 + l15;
#pragma unroll
      for (int r = 0; r < 4; ++r) {
        int row = base + wr * 64 + mf * 16 + (lane >> 4) * 4 + r;
        G[(size_t)row * CO + col] = f2bf(accG[mf][nf][r]);
        C[(size_t)row * CO + col] = f2bf(accC[mf][nf][r] + sh[nf]);
      }
    }
}

// ------- gather + leaky + max over k; G and C read as bf16 -----------------
// XCD-locality: batch = g*8 + (blockIdx%8) so a batch stays on one XCD L2.
template <int CO>
__global__ __launch_bounds__(256) void gatherbf_kernel(
    const unsigned short* __restrict__ G, const unsigned short* __restrict__ C,
    const int* __restrict__ idx, unsigned short* __restrict__ outHi) {
  constexpr int O4 = CO / 4;
  constexpr int PPB = 256 / O4;        // points per block
  constexpr int BPB = N / PPB;         // blocks per batch
  constexpr int GRP = 8 * BPB;         // blocks per batch-group
  const int i = (int)blockIdx.x;
  const int g = i / GRP;
  const int j = i % GRP;
  const int b = g * 8 + (j & 7);
  const int chunk = j >> 3;
  const int tid = (int)threadIdx.x;
  const int o4 = tid % O4;
  const int lp = tid / O4;
  const size_t bn = (size_t)b * N + chunk * PPB + lp;
  const int* ip = &idx[bn * KNN_K];
  const unsigned short* Gb = G + (size_t)b * N * CO;
  ushort4 cu = *(const ushort4*)&C[bn * CO + o4 * 4];
  float4 cv = make_float4(bf2f(cu.x), bf2f(cu.y), bf2f(cu.z), bf2f(cu.w));
  float4 m = make_float4(-1e30f, -1e30f, -1e30f, -1e30f);
#pragma unroll
  for (int k = 0; k < KNN_K; ++k) {
    int nb = ip[k];
    ushort4 gu = *(const ushort4*)&Gb[(size_t)nb * CO + o4 * 4];
    m.x = lrelu_max(m.x, bf2f(gu.x) + cv.x);
    m.y = lrelu_max(m.y, bf2f(gu.y) + cv.y);
    m.z = lrelu_max(m.z, bf2f(gu.z) + cv.z);
    m.w = lrelu_max(m.w, bf2f(gu.w) + cv.w);
  }
  ushort4 hi;
  hi.x = f2bf(m.x); hi.y = f2bf(m.y); hi.z = f2bf(m.z); hi.w = f2bf(m.w);
  *(ushort4*)&outHi[bn * CO + o4 * 4] = hi;
}

// ---------------- last layer: gather + max over k, partial max over n ------
template <int CO>
__global__ __launch_bounds__(256) void gather_last_kernel(
    const unsigned short* __restrict__ G0, const unsigned short* __restrict__ C0,
    const unsigned short* __restrict__ G1, const unsigned short* __restrict__ C1,
    const int* __restrict__ idx, float* __restrict__ part) {
  constexpr int O4 = CO / 4;
  constexpr int PL = 256 / O4;
  constexpr int ITER = 128 / PL;
  const int h = (int)blockIdx.y;
  const unsigned short* G = h ? G1 : G0;
  const unsigned short* C = h ? C1 : C0;
  float* pt = part + (size_t)h * B * 16 * CO;
  const int i = (int)blockIdx.x;
  const int g = i / 128;
  const int j = i % 128;
  const int b = g * 8 + (j & 7);
  const int chunk = j >> 3;  // 0..15
  int tid = (int)threadIdx.x;
  int o4 = tid % O4;
  int pl = tid / O4;
  const unsigned short* Gb = G + (size_t)b * N * CO;
  float4 m = make_float4(-1e30f, -1e30f, -1e30f, -1e30f);
  for (int it = 0; it < ITER; ++it) {
    int n = chunk * 128 + it * PL + pl;
    size_t bn = (size_t)b * N + n;
    const int* ip = &idx[bn * KNN_K];
    ushort4 cu = *(const ushort4*)&C[bn * CO + o4 * 4];
    float4 cv = make_float4(bf2f(cu.x), bf2f(cu.y), bf2f(cu.z), bf2f(cu.w));
#pragma unroll
    for (int k = 0; k < KNN_K; ++k) {
      int nb = ip[k];
      ushort4 gu = *(const ushort4*)&Gb[(size_t)nb * CO + o4 * 4];
      m.x = lrelu_max(m.x, bf2f(gu.x) + cv.x);
      m.y = lrelu_max(m.y, bf2f(gu.y) + cv.y);
      m.z = lrelu_max(m.z, bf2f(gu.z) + cv.z);
      m.w = lrelu_max(m.w, bf2f(gu.w) + cv.w);
    }
  }
  __shared__ __align__(16) float4 red[256];
  red[tid] = m;
  __syncthreads();
  for (int s = 128; s >= O4; s >>= 1) {
    if (tid < s) {
      float4 a = red[tid], bb = red[tid + s];
      red[tid] = make_float4(fmaxf(a.x, bb.x), fmaxf(a.y, bb.y),
                             fmaxf(a.z, bb.z), fmaxf(a.w, bb.w));
    }
    __syncthreads();
  }
  if (tid < O4) {
    *(float4*)&pt[((size_t)(b * 16 + chunk)) * CO + tid * 4] = red[tid];
  }
}

// --------- fused final reduce over both 128-channel halves (grid.y=2) ------
template <int CO>
__global__ __launch_bounds__(256) void reduce2_kernel(const float* __restrict__ part,
                                                      float* __restrict__ out) {
  constexpr int O4 = CO / 4;
  int half = blockIdx.y;
  const float* p = part + (size_t)half * B * 16 * CO;
  int gid = blockIdx.x * 256 + (int)threadIdx.x;  // 0 .. B*O4-1
  int b = gid / O4;
  int o4 = gid % O4;
  float4 m = make_float4(-1e30f, -1e30f, -1e30f, -1e30f);
  for (int ch = 0; ch < 16; ++ch) {
    float4 v = *(const float4*)&p[((size_t)(b * 16 + ch)) * CO + o4 * 4];
    m.x = fmaxf(m.x, v.x); m.y = fmaxf(m.y, v.y);
    m.z = fmaxf(m.z, v.z); m.w = fmaxf(m.w, v.w);
  }
  *(float4*)&out[(size_t)b * 256 + half * 128 + o4 * 4] = m;
}

extern "C" void kernel_launch(void* const* d_in, const int* in_sizes, int n_in,
                              void* d_out, int out_size, void* d_ws, size_t ws_size,
                              hipStream_t stream) {
  const float* xyz = (const float*)d_in[0];
  const float* W0 = (const float*)d_in[1];
  const float* s0 = (const float*)d_in[2];
  const float* b0 = (const float*)d_in[3];
  const float* W1 = (const float*)d_in[4];
  const float* s1 = (const float*)d_in[5];
  const float* b1 = (const float*)d_in[6];
  const float* W2 = (const float*)d_in[7];
  const float* s2 = (const float*)d_in[8];
  const float* b2 = (const float*)d_in[9];
  float* out = (float*)d_out;

  const size_t MB = 1024 * 1024;
  const bool wide = ws_size >= 88 * MB;  // room for G2/C2 (fused layer-3)
  char* ws = (char*)d_ws;
  int* idx = (int*)ws;                                       // 2 MB
  unsigned short* Fb = (unsigned short*)(ws + 2 * MB);       // 16 MB bf16 feats
  unsigned short* Gb = (unsigned short*)(ws + 18 * MB);      // 16 MB bf16 G
  unsigned short* Cb = (unsigned short*)(ws + 34 * MB);      // 16 MB bf16 C
  unsigned short* G2 = wide ? (unsigned short*)(ws + 50 * MB) : Gb;  // 16 MB
  unsigned short* C2 = wide ? (unsigned short*)(ws + 66 * MB) : Cb;  // 16 MB
  size_t tail = wide ? 82 * MB : 50 * MB;
  unsigned short* wb1 = (unsigned short*)(ws + tail);              // 64 KB
  unsigned short* wb2 = (unsigned short*)(ws + tail + 64 * 1024);  // 256 KB
  float* part = (float*)(ws + tail + 512 * 1024);            // 512 KB (2 halves)

  // fused: knn (1024) | layer-1 transform (1024) | wprep1 (32) | wprep2 (128)
  front_kernel<<<2208, 256, 0, stream>>>(xyz, idx, W0, s0, b0, Gb, Cb, W1, s1,
                                         wb1, W2, s2, wb2);
  gatherbf_kernel<64><<<M * 16 / 256, 256, 0, stream>>>(Gb, Cb, idx, Fb);

  // Layer 2: K=64, CO=128 — MFMA 2-pass (W hi+lo, A bf16)
  mfma_transform_kernel<64, 128><<<dim3(M / 128, 2, 1), 256, 0, stream>>>(
      Fb, wb1, b1, Gb, Cb, Gb, Cb, (size_t)64 * 128, 0, 0);
  gatherbf_kernel<128><<<M * 32 / 256, 256, 0, stream>>>(Gb, Cb, idx, Fb);

  // Layer 3: K=128, CO=256 in two 128-channel halves — MFMA 2-pass
  if (wide) {
    mfma_transform_kernel<128, 128><<<dim3(M / 128, 2, 2), 256, 0, stream>>>(
        Fb, wb2, b2, Gb, Cb, G2, C2, (size_t)128 * 256, (size_t)128 * 128, 128);
    gather_last_kernel<128><<<dim3(B * 16, 2), 256, 0, stream>>>(
        Gb, Cb, G2, C2, idx, part);
  } else {
    for (int h = 0; h < 2; ++h) {
      mfma_transform_kernel<128, 128><<<dim3(M / 128, 2, 1), 256, 0, stream>>>(
          Fb, wb2 + (size_t)h * 128 * 128, b2 + h * 128, Gb, Cb, Gb, Cb,
          (size_t)128 * 256, 0, 0);
      gather_last_kernel<128><<<dim3(B * 16, 1), 256, 0, stream>>>(
          Gb, Cb, Gb, Cb, idx, part + (size_t)h * B * 16 * 128);
    }
  }
  reduce2_kernel<128><<<dim3(B * 128 / 4 / 256, 2), 256, 0, stream>>>(part, out);
}